// Round 13
// baseline (1006.778 us; speedup 1.0000x reference)
//
#include <hip/hip_runtime.h>

typedef __attribute__((ext_vector_type(8))) short bf16x8;
typedef __attribute__((ext_vector_type(4))) float f32x4;
typedef unsigned short ushort_t;

__device__ inline ushort_t bf16_trunc(float f) { return (ushort_t)(__float_as_uint(f) >> 16); }
__device__ inline float bf16_to_f(ushort_t u) { return __uint_as_float(((unsigned int)u) << 16); }

// ---------------------------------------------------------------------------
// NCHW fp32 -> NHWC bf16 hi/lo planes (A-operand for conv_mfma).
// ---------------------------------------------------------------------------
template<int CI, int HW>
__global__ __launch_bounds__(256)
void convert_nhwc(const float* __restrict__ x, ushort_t* __restrict__ hi,
                  ushort_t* __restrict__ lo, int Mtotal)
{
    const int m = blockIdx.x * 256 + threadIdx.x;
    if (m >= Mtotal) return;
    const int b = m / HW, pos = m - b * HW;
    const float* xp = x + (size_t)b * CI * HW + pos;
    ushort_t* hp = hi + (size_t)m * CI;
    ushort_t* lp = lo + (size_t)m * CI;
#pragma unroll
    for (int ci = 0; ci < CI; ++ci) {
        const float v = xp[(size_t)ci * HW];
        const ushort_t h = bf16_trunc(v);
        hp[ci] = h;
        lp[ci] = bf16_trunc(v - bf16_to_f(h));
    }
}

// ---------------------------------------------------------------------------
// Weight prep for conv_mfma: OIHW fp32 -> [kk][n][ci] hi/lo, zero-padded.
// ---------------------------------------------------------------------------
template<int CI, int KK, int KKPAD, int NPAD, int OC>
__global__ __launch_bounds__(256)
void wprep(const float* __restrict__ w, ushort_t* __restrict__ bhi, ushort_t* __restrict__ blo)
{
    const int idx = blockIdx.x * 256 + threadIdx.x;
    if (idx >= KKPAD * NPAD * CI) return;
    const int kk  = idx / (NPAD * CI);
    const int rem = idx - kk * (NPAD * CI);
    const int n   = rem / CI;
    const int ci  = rem - n * CI;
    const float v = (kk < KK && n < OC) ? w[((size_t)n * CI + ci) * KK + kk] : 0.f;
    const ushort_t h = bf16_trunc(v);
    bhi[idx] = h;
    blo[idx] = bf16_trunc(v - bf16_to_f(h));
}

// ---------------------------------------------------------------------------
// Weight prep for deform_mfma: pack [kslot = pass*TPAD+tap][n][j=ci_in_pass].
// ---------------------------------------------------------------------------
template<int CI, int KK, int TPAD, int NPAD, int OC>
__global__ __launch_bounds__(256)
void wprep_d(const float* __restrict__ w, ushort_t* __restrict__ bhi, ushort_t* __restrict__ blo)
{
    constexpr int NPASS = (CI + 7) / 8;
    constexpr int TOTAL = NPASS * TPAD * NPAD * 8;
    const int idx = blockIdx.x * 256 + threadIdx.x;
    if (idx >= TOTAL) return;
    const int j     = idx & 7;
    const int n     = (idx >> 3) % NPAD;
    const int kslot = (idx >> 3) / NPAD;
    const int pass  = kslot / TPAD;
    const int tap   = kslot - pass * TPAD;
    const int ci    = pass * 8 + j;
    const float v = (tap < KK && n < OC && ci < CI) ? w[((size_t)n * CI + ci) * KK + tap] : 0.f;
    const ushort_t h = bf16_trunc(v);
    bhi[idx] = h;
    blo[idx] = bf16_trunc(v - bf16_to_f(h));
}

// ---------------------------------------------------------------------------
// MFMA implicit-im2col conv. Valid-m indexing + double-buffered LDS B slab.
// ---------------------------------------------------------------------------
template<int CI, int K, int H, int W, int Ho, int Wo, int OC, int NTTOT, int NT0, int KSTEPS>
__global__ __launch_bounds__(256)
void conv_mfma(const ushort_t* __restrict__ Xhi, const ushort_t* __restrict__ Xlo,
               const ushort_t* __restrict__ Bhi, const ushort_t* __restrict__ Blo,
               const float* __restrict__ bias, float* __restrict__ out, int Mtotal)
{
    constexpr int NPAD = NTTOT * 16;
    constexpr int HW   = H * W;
    constexpr int HoWo = Ho * Wo;
    constexpr int TKS  = 32 / CI;
    constexpr int ROWS = TKS * NT0 * 16;
    constexpr int BSTR = CI + 8;
    constexpr int CH8  = CI / 8;
    constexpr int CHUNKS = ROWS * CH8;

    __shared__ __align__(16) ushort_t sBh[2][ROWS * BSTR];
    __shared__ __align__(16) ushort_t sBl[2][ROWS * BSTR];

    const int tid  = threadIdx.x;
    const int lane = tid & 63;
    const int wid  = tid >> 6;
    const int col  = lane & 15;
    const int quad = lane >> 4;

    const int mBase  = blockIdx.x * 256 + wid * 64;
    const int ntBase = blockIdx.y * NT0;

    int aBase[4];
#pragma unroll
    for (int mt = 0; mt < 4; ++mt) {
        int mm = mBase + mt * 16 + col;
        if (mm >= Mtotal) mm = Mtotal - 1;
        const int b   = mm / HoWo;
        const int pos = mm - b * HoWo;
        const int oy  = pos / Wo;
        const int ox  = pos - oy * Wo;
        aBase[mt] = (b * HW + oy * W + ox) * CI;
    }

    f32x4 acc[4][NT0];
#pragma unroll
    for (int mt = 0; mt < 4; ++mt)
#pragma unroll
        for (int nt = 0; nt < NT0; ++nt) acc[mt][nt] = (f32x4){0.f, 0.f, 0.f, 0.f};

    auto loadSlab = [&](int ks, int buf) {
        const int tap0 = ks * TKS;
        for (int i = tid; i < CHUNKS; i += 256) {
            const int row = i / CH8;
            const int c8  = i - row * CH8;
            const int t   = row / (NT0 * 16);
            const int nn  = row - t * (NT0 * 16);
            int n = ntBase * 16 + nn;
            if (n > NPAD - 1) n = NPAD - 1;
            const int g = ((tap0 + t) * NPAD + n) * CI + c8 * 8;
            *(bf16x8*)(sBh[buf] + row * BSTR + c8 * 8) = *(const bf16x8*)(Bhi + g);
            *(bf16x8*)(sBl[buf] + row * BSTR + c8 * 8) = *(const bf16x8*)(Blo + g);
        }
    };

    loadSlab(0, 0);
    __syncthreads();

#pragma unroll
    for (int ks = 0; ks < KSTEPS; ++ks) {
        if (ks + 1 < KSTEPS) loadSlab(ks + 1, (ks + 1) & 1);

        const int k0   = ks * 32 + quad * 8;
        const int tap  = k0 / CI;
        const int tloc = tap - ks * TKS;
        const int ci   = k0 - tap * CI;
        const int dkk  = (tap / K) * W + (tap - (tap / K) * K);

        bf16x8 ah[4], al[4];
#pragma unroll
        for (int mt = 0; mt < 4; ++mt) {
            const int aoff = aBase[mt] + dkk * CI + ci;
            ah[mt] = *(const bf16x8*)(Xhi + aoff);
            al[mt] = *(const bf16x8*)(Xlo + aoff);
        }
        const ushort_t* __restrict__ bhp = sBh[ks & 1];
        const ushort_t* __restrict__ blp = sBl[ks & 1];
#pragma unroll
        for (int nt = 0; nt < NT0; ++nt) {
            const int ntg = ntBase + nt;
            if (ntg < NTTOT) {
                const int lrow = ((tloc * NT0 + nt) * 16 + col) * BSTR + ci;
                const bf16x8 bh = *(const bf16x8*)(bhp + lrow);
                const bf16x8 bl = *(const bf16x8*)(blp + lrow);
#pragma unroll
                for (int mt = 0; mt < 4; ++mt) {
                    acc[mt][nt] = __builtin_amdgcn_mfma_f32_16x16x32_bf16(ah[mt], bh, acc[mt][nt], 0, 0, 0);
                    acc[mt][nt] = __builtin_amdgcn_mfma_f32_16x16x32_bf16(al[mt], bh, acc[mt][nt], 0, 0, 0);
                    acc[mt][nt] = __builtin_amdgcn_mfma_f32_16x16x32_bf16(ah[mt], bl, acc[mt][nt], 0, 0, 0);
                }
            }
        }
        __syncthreads();
    }

#pragma unroll
    for (int mt = 0; mt < 4; ++mt) {
#pragma unroll
        for (int nt = 0; nt < NT0; ++nt) {
            const int ntg = ntBase + nt;
            const int n   = ntg * 16 + col;
            if (ntg < NTTOT && n < OC) {
                const float bv = bias[n];
#pragma unroll
                for (int r = 0; r < 4; ++r) {
                    const int m = mBase + mt * 16 + quad * 4 + r;
                    if (m < Mtotal) {
                        const int b   = m / HoWo;
                        const int pos = m - b * HoWo;
                        out[((size_t)b * OC + n) * HoWo + pos] = acc[mt][nt][r] + bv;
                    }
                }
            }
        }
    }
}

// ---------------------------------------------------------------------------
// MFMA deformable conv (stages 2-5). LDS tile now STRIDE=8 floats/pixel
// (exactly 8 channels, 32B) with 1-bit XOR swizzle: channel c of pixel p at
// offset c ^ ((p&1)<<2). Start-bank classes {0,4,...,28} (same 8-way spread
// as old stride-12) but tile shrinks 40->27KB -> 4 blocks/CU (32 waves).
// ---------------------------------------------------------------------------
template<int K, int CI, int CO, int H, int W, int Ho, int Wo, bool RELU,
         int MT, int TPAD>
__global__ __launch_bounds__(MT * 64)
void deform_mfma(const float* __restrict__ x, const float* __restrict__ off,
                 const ushort_t* __restrict__ Bph, const ushort_t* __restrict__ Bpl,
                 const float* __restrict__ bias, float* __restrict__ out)
{
    constexpr int KK     = K * K;
    constexpr int HW     = H * W;
    constexpr int HoWo   = Ho * Wo;
    constexpr int NPASS  = CI / 8;
    constexpr int NT     = (CO + 15) / 16;
    constexpr int NPAD   = NT * 16;
    constexpr int nMB    = (HoWo + MT * 16 - 1) / (MT * 16);
    constexpr int THREADS = MT * 64;
    __shared__ __align__(16) float tile[HW * 8];

    const int b    = blockIdx.x / nMB;
    const int mb   = blockIdx.x - b * nMB;
    const int tid  = threadIdx.x;
    const int wid  = tid >> 6;
    const int lane = tid & 63;
    const int col  = lane & 15;
    const int quad = lane >> 4;

    const int pixel0 = (mb * MT + wid) * 16;
    const int s      = pixel0 + col;
    const bool am    = (s < HoWo);
    const int oy = s / Wo, ox = s - oy * Wo;

    const float* offB = off + (size_t)b * 2 * KK * HoWo;

    f32x4 acc[NT];
#pragma unroll
    for (int nt = 0; nt < NT; ++nt) acc[nt] = (f32x4){0.f, 0.f, 0.f, 0.f};

    for (int pass = 0; pass < NPASS; ++pass) {
        const int cbase = pass * 8;
        __syncthreads();
        for (int pos = tid; pos < HW; pos += THREADS) {
            const int sw = (pos & 1) << 2;
            f32x4 v0, v1;
#pragma unroll
            for (int c = 0; c < 4; ++c)
                v0[c] = x[((size_t)b * CI + (cbase + c)) * HW + pos];
#pragma unroll
            for (int c = 0; c < 4; ++c)
                v1[c] = x[((size_t)b * CI + (cbase + 4 + c)) * HW + pos];
            *(f32x4*)(tile + pos * 8 + sw)       = v0;   // channels 0..3
            *(f32x4*)(tile + pos * 8 + (sw ^ 4)) = v1;   // channels 4..7
        }
        __syncthreads();

#pragma unroll
        for (int tg = 0; tg < TPAD / 4; ++tg) {
            const int tap = tg * 4 + quad;
            bf16x8 ahi = (bf16x8){0,0,0,0,0,0,0,0};
            bf16x8 alo = (bf16x8){0,0,0,0,0,0,0,0};

            if (am && tap < KK) {
                const float dy = offB[(size_t)(2 * tap + 0) * HoWo + s];
                const float dx = offB[(size_t)(2 * tap + 1) * HoWo + s];
                const float py = (float)(tap / K + oy) + dy;
                const float px = (float)(tap % K + ox) + dx;
                const float y0f = floorf(py), x0f = floorf(px);
                const float wy = py - y0f, wx = px - x0f;
                const int y0 = (int)y0f, x0 = (int)x0f;
                const int y1 = y0 + 1,   x1 = x0 + 1;

                const float m00 = (y0 >= 0 && y0 < H && x0 >= 0 && x0 < W) ? 1.f : 0.f;
                const float m01 = (y0 >= 0 && y0 < H && x1 >= 0 && x1 < W) ? 1.f : 0.f;
                const float m10 = (y1 >= 0 && y1 < H && x0 >= 0 && x0 < W) ? 1.f : 0.f;
                const float m11 = (y1 >= 0 && y1 < H && x1 >= 0 && x1 < W) ? 1.f : 0.f;

                const float w00 = (1.f - wy) * (1.f - wx) * m00;
                const float w01 = (1.f - wy) * wx         * m01;
                const float w10 = wy         * (1.f - wx) * m10;
                const float w11 = wy         * wx         * m11;

                const int y0c = min(max(y0, 0), H - 1), y1c = min(max(y1, 0), H - 1);
                const int x0c = min(max(x0, 0), W - 1), x1c = min(max(x1, 0), W - 1);
                const int p00 = y0c * W + x0c, p01 = y0c * W + x1c;
                const int p10 = y1c * W + x0c, p11 = y1c * W + x1c;
                const int s00 = (p00 & 1) << 2, s01 = (p01 & 1) << 2;
                const int s10 = (p10 & 1) << 2, s11 = (p11 & 1) << 2;

                float v00[8], v01[8], v10[8], v11[8];
                *(f32x4*)(v00)     = *(const f32x4*)(tile + p00 * 8 + s00);
                *(f32x4*)(v00 + 4) = *(const f32x4*)(tile + p00 * 8 + (s00 ^ 4));
                *(f32x4*)(v01)     = *(const f32x4*)(tile + p01 * 8 + s01);
                *(f32x4*)(v01 + 4) = *(const f32x4*)(tile + p01 * 8 + (s01 ^ 4));
                *(f32x4*)(v10)     = *(const f32x4*)(tile + p10 * 8 + s10);
                *(f32x4*)(v10 + 4) = *(const f32x4*)(tile + p10 * 8 + (s10 ^ 4));
                *(f32x4*)(v11)     = *(const f32x4*)(tile + p11 * 8 + s11);
                *(f32x4*)(v11 + 4) = *(const f32x4*)(tile + p11 * 8 + (s11 ^ 4));
#pragma unroll
                for (int j = 0; j < 8; ++j) {
                    const float sv = fmaf(v11[j], w11, fmaf(v10[j], w10,
                                     fmaf(v01[j], w01, v00[j] * w00)));
                    const ushort_t h = bf16_trunc(sv);
                    ahi[j] = (short)h;
                    alo[j] = (short)bf16_trunc(sv - bf16_to_f(h));
                }
            }

            const size_t kslot = (size_t)(pass * TPAD + tap);
#pragma unroll
            for (int nt = 0; nt < NT; ++nt) {
                const bf16x8 bh = *(const bf16x8*)(Bph + (kslot * NPAD + nt * 16 + col) * 8);
                const bf16x8 bl = *(const bf16x8*)(Bpl + (kslot * NPAD + nt * 16 + col) * 8);
                acc[nt] = __builtin_amdgcn_mfma_f32_16x16x32_bf16(ahi, bh, acc[nt], 0, 0, 0);
                acc[nt] = __builtin_amdgcn_mfma_f32_16x16x32_bf16(alo, bh, acc[nt], 0, 0, 0);
                acc[nt] = __builtin_amdgcn_mfma_f32_16x16x32_bf16(ahi, bl, acc[nt], 0, 0, 0);
            }
        }
    }

#pragma unroll
    for (int nt = 0; nt < NT; ++nt) {
        const int n = nt * 16 + col;
        if (n < CO) {
            const float bv = bias[n];
#pragma unroll
            for (int r = 0; r < 4; ++r) {
                const int m = pixel0 + quad * 4 + r;
                if (m < HoWo) {
                    float v = acc[nt][r] + bv;
                    if (RELU) v = fmaxf(v, 0.f);
                    out[((size_t)b * CO + n) * HoWo + m] = v;
                }
            }
        }
    }
}

// ---------------------------------------------------------------------------
// Scalar LDS deform (stages 1 and 6).
// ---------------------------------------------------------------------------
template<int K, int CI, int CO, int H, int W, int Ho, int Wo, bool RELU,
         int CSPLIT, int STRIDE, int THREADS, int SPLIT>
__global__ __launch_bounds__(THREADS)
void deform_lds(const float* __restrict__ x, const float* __restrict__ off,
                const float* __restrict__ w, const float* __restrict__ bias,
                float* __restrict__ out)
{
    constexpr int KK    = K * K;
    constexpr int HW    = H * W;
    constexpr int HoWo  = Ho * Wo;
    constexpr int NPASS = CI / CSPLIT;
    constexpr int CHUNK = (HoWo + SPLIT - 1) / SPLIT;
    static_assert(CHUNK <= THREADS, "chunk must fit in one block");
    __shared__ __align__(16) float tile[HW * STRIDE];

    const int b   = blockIdx.x / SPLIT;
    const int sp  = blockIdx.x - b * SPLIT;
    const int tid = threadIdx.x;
    const int s   = sp * CHUNK + tid;
    const bool active = (tid < CHUNK) && (s < HoWo);

    const int oy = s / Wo, ox = s - oy * Wo;
    const float* offp = off + ((size_t)b * 2 * KK) * HoWo + s;

    float acc[CO];
#pragma unroll
    for (int o = 0; o < CO; ++o) acc[o] = 0.f;

    for (int pass = 0; pass < NPASS; ++pass) {
        const int cbase = pass * CSPLIT;
        __syncthreads();
        for (int pos = tid; pos < HW; pos += THREADS) {
#pragma unroll
            for (int c = 0; c < CSPLIT; ++c)
                tile[pos * STRIDE + c] = x[((size_t)b * CI + (cbase + c)) * HW + pos];
        }
        __syncthreads();

        if (active) {
            for (int kk = 0; kk < KK; ++kk) {
                const float dy = offp[(size_t)(2 * kk + 0) * HoWo];
                const float dx = offp[(size_t)(2 * kk + 1) * HoWo];
                const float py = (float)(kk / K + oy) + dy;
                const float px = (float)(kk % K + ox) + dx;
                const float y0f = floorf(py), x0f = floorf(px);
                const float wy = py - y0f, wx = px - x0f;
                const int y0 = (int)y0f, x0 = (int)x0f;
                const int y1 = y0 + 1,   x1 = x0 + 1;

                const float m00 = (y0 >= 0 && y0 < H && x0 >= 0 && x0 < W) ? 1.f : 0.f;
                const float m01 = (y0 >= 0 && y0 < H && x1 >= 0 && x1 < W) ? 1.f : 0.f;
                const float m10 = (y1 >= 0 && y1 < H && x0 >= 0 && x0 < W) ? 1.f : 0.f;
                const float m11 = (y1 >= 0 && y1 < H && x1 >= 0 && x1 < W) ? 1.f : 0.f;

                const float w00 = (1.f - wy) * (1.f - wx) * m00;
                const float w01 = (1.f - wy) * wx         * m01;
                const float w10 = wy         * (1.f - wx) * m10;
                const float w11 = wy         * wx         * m11;

                const int y0c = min(max(y0, 0), H - 1), y1c = min(max(y1, 0), H - 1);
                const int x0c = min(max(x0, 0), W - 1), x1c = min(max(x1, 0), W - 1);
                const int i00 = (y0c * W + x0c) * STRIDE;
                const int i01 = (y0c * W + x1c) * STRIDE;
                const int i10 = (y1c * W + x0c) * STRIDE;
                const int i11 = (y1c * W + x1c) * STRIDE;

                if constexpr (CSPLIT % 4 == 0) {
#pragma unroll
                    for (int cg = 0; cg < CSPLIT; cg += 4) {
                        const f32x4 v00 = *(const f32x4*)(tile + i00 + cg);
                        const f32x4 v01 = *(const f32x4*)(tile + i01 + cg);
                        const f32x4 v10 = *(const f32x4*)(tile + i10 + cg);
                        const f32x4 v11 = *(const f32x4*)(tile + i11 + cg);
#pragma unroll
                        for (int j = 0; j < 4; ++j) {
                            const float sv = fmaf(v11[j], w11, fmaf(v10[j], w10,
                                             fmaf(v01[j], w01, v00[j] * w00)));
#pragma unroll
                            for (int o = 0; o < CO; ++o)
                                acc[o] = fmaf(sv, w[(size_t)(o * CI + cbase + cg + j) * KK + kk], acc[o]);
                        }
                    }
                } else {
                    const float sv = fmaf(tile[i11], w11, fmaf(tile[i10], w10,
                                     fmaf(tile[i01], w01, tile[i00] * w00)));
#pragma unroll
                    for (int o = 0; o < CO; ++o)
                        acc[o] = fmaf(sv, w[(size_t)(o * CI + cbase) * KK + kk], acc[o]);
                }
            }
        }
    }

    if (active) {
        float* op = out + ((size_t)b * CO) * HoWo + s;
#pragma unroll
        for (int o = 0; o < CO; ++o) {
            float v = acc[o] + bias[o];
            if (RELU) v = fmaxf(v, 0.f);
            op[(size_t)o * HoWo] = v;
        }
    }
}

// ---------------------------------------------------------------------------
// Register-tiled direct VALID conv (stages 1 and 6 offset convs).
// ---------------------------------------------------------------------------
template<int K, int CI, int NOC, int OC, int H, int W, int Ho, int Wo, int PIX>
__global__ __launch_bounds__(256)
void conv_tile(const float* __restrict__ x, const float* __restrict__ w,
               const float* __restrict__ bias, float* __restrict__ out)
{
    constexpr int KK   = K * K;
    constexpr int HoWo = Ho * Wo;
    constexpr int WoG  = (Wo + PIX - 1) / PIX;
    constexpr int G    = Ho * WoG;
    constexpr int XV   = PIX + K - 1;

    const int oc0   = blockIdx.y * NOC;
    const int g_all = blockIdx.x * 256 + threadIdx.x;
    const int b     = g_all / G;
    const int g     = g_all - b * G;
    const int oy    = g / WoG;
    const int ox0   = (g - oy * WoG) * PIX;

    const float* xbp = x + (b * CI) * (H * W) + oy * W + ox0;
    const float* wp  = w + oc0 * (CI * KK);

    float acc[PIX][NOC];
#pragma unroll
    for (int p = 0; p < PIX; ++p)
#pragma unroll
        for (int j = 0; j < NOC; ++j) acc[p][j] = bias[oc0 + j];

    const int lim = W - 1 - ox0;

    for (int ci = 0; ci < CI; ++ci) {
        const float* xc = xbp + ci * (H * W);
#pragma unroll
        for (int ky = 0; ky < K; ++ky) {
            float xv[XV];
#pragma unroll
            for (int i = 0; i < XV; ++i) {
                const int off = (i <= lim) ? i : lim;
                xv[i] = xc[ky * W + off];
            }
#pragma unroll
            for (int kx = 0; kx < K; ++kx) {
#pragma unroll
                for (int p = 0; p < PIX; ++p) {
                    const float v = xv[p + kx];
#pragma unroll
                    for (int j = 0; j < NOC; ++j)
                        acc[p][j] = fmaf(v, wp[j * (CI * KK) + ci * KK + ky * K + kx], acc[p][j]);
                }
            }
        }
    }

    float* op = out + (b * OC + oc0) * HoWo + oy * Wo + ox0;
#pragma unroll
    for (int p = 0; p < PIX; ++p) {
        if (ox0 + p < Wo) {
#pragma unroll
            for (int j = 0; j < NOC; ++j) op[j * HoWo + p] = acc[p][j];
        }
    }
}

// ---------------------------------------------------------------------------
// FC weight transpose: wT[i][j] = w[j][i].
// ---------------------------------------------------------------------------
template<int IN, int OUT>
__global__ __launch_bounds__(256)
void wtrans(const float* __restrict__ w, float* __restrict__ wt)
{
    const int idx = blockIdx.x * 256 + threadIdx.x;
    if (idx >= IN * OUT) return;
    const int i = idx / OUT, j = idx - i * OUT;
    wt[idx] = w[(size_t)j * IN + i];
}

// ---------------------------------------------------------------------------
// Coalesced FC with transposed weights.
// ---------------------------------------------------------------------------
template<int IN, int OUT, bool RELU>
__global__ __launch_bounds__(256)
void fc_t(const float* __restrict__ h, const float* __restrict__ wt,
          const float* __restrict__ bias, float* __restrict__ out, int B)
{
    const int idx = blockIdx.x * 256 + threadIdx.x;
    if (idx >= B * OUT) return;
    const int b = idx / OUT;
    const int j = idx - b * OUT;
    const float* hb = h + (size_t)b * IN;
    float acc = bias[j];
#pragma unroll 4
    for (int i = 0; i < IN; ++i)
        acc = fmaf(hb[i], wt[(size_t)i * OUT + j], acc);
    if (RELU) acc = fmaxf(acc, 0.f);
    out[idx] = acc;
}

// ---------------------------------------------------------------------------
extern "C" void kernel_launch(void* const* d_in, const int* in_sizes, int n_in,
                              void* d_out, int out_size, void* d_ws, size_t ws_size,
                              hipStream_t stream)
{
    const int B = 512;
    const float* x = (const float*)d_in[0];
    const float *ow[6], *ob[6], *w[6], *bi[6];
    for (int i = 0; i < 6; ++i) {
        ow[i] = (const float*)d_in[1 + 4 * i];
        ob[i] = (const float*)d_in[2 + 4 * i];
        w[i]  = (const float*)d_in[3 + 4 * i];
        bi[i] = (const float*)d_in[4 + 4 * i];
    }
    const float* fc1w = (const float*)d_in[25];
    const float* fc1b = (const float*)d_in[26];
    const float* fc2w = (const float*)d_in[27];
    const float* fc2b = (const float*)d_in[28];
    float* out = (float*)d_out;

    float* P   = (float*)d_ws;        // 14M floats
    float* Q   = P  + 14000000;       // 14M floats
    float* OFF = Q  + 14000000;       // 18.2M floats
    float* Z   = OFF + 18200000;      // fc intermediate
    ushort_t* WBhi = (ushort_t*)(Z + 200000);   // conv_mfma weights
    ushort_t* WBlo = WBhi + 200000;
    ushort_t* WDhi = WBlo + 200000;             // deform_mfma weights
    ushort_t* WDlo = WDhi + 200000;
    float* WT1 = (float*)(WDlo + 200000);       // fc1 wT: 676*256 floats
    float* WT2 = WT1 + 173056;                  // fc2 wT: 256*10 floats

    const dim3 blk(256);
    #define GRIDT(Ho, Wo, PIX, NG) dim3((B * (Ho) * (((Wo) + (PIX) - 1) / (PIX)) + 255) / 256, (NG), 1)
    #define CEILDIV(a, b) (((a) + (b) - 1) / (b))

    // ---- stage 1: input x (CI=1). conv_tile -> OFF; deform_lds -> P ----
    conv_tile<3, 1, 6, 18, 33, 33, 31, 31, 4><<<GRIDT(31, 31, 4, 3), blk, 0, stream>>>(x, ow[0], ob[0], OFF);
    deform_lds<3, 1, 16, 33, 33, 31, 31, true, 1, 1, 512, 2><<<dim3(B * 2), dim3(512), 0, stream>>>(x, OFF, w[0], bi[0], P);

    // ---- stage 2: CI=16 K=3 31x31->29x29 OC(off)=18 CO=32. P -> Q ----
    {
        const int Mc = B * 961;
        const int Mv = B * 841;
        ushort_t* Xhi = (ushort_t*)Q;
        ushort_t* Xlo = Xhi + (size_t)(Mc + 2048) * 16;
        convert_nhwc<16, 961><<<CEILDIV(Mc, 256), blk, 0, stream>>>(P, Xhi, Xlo, Mc);
        wprep<16, 9, 10, 32, 18><<<CEILDIV(10 * 32 * 16, 256), blk, 0, stream>>>(ow[1], WBhi, WBlo);
        conv_mfma<16, 3, 31, 31, 29, 29, 18, 2, 2, 5><<<dim3(CEILDIV(Mv, 256), 1), blk, 0, stream>>>(Xhi, Xlo, WBhi, WBlo, ob[1], OFF, Mv);
        wprep_d<16, 9, 12, 32, 32><<<CEILDIV(2 * 12 * 32 * 8, 256), blk, 0, stream>>>(w[1], WDhi, WDlo);
        deform_mfma<3, 16, 32, 31, 31, 29, 29, true, 8, 12><<<dim3(B * 7), dim3(512), 0, stream>>>(P, OFF, WDhi, WDlo, bi[1], Q);
    }
    // ---- stage 3: CI=32 K=5 29x29->25x25 OC(off)=50 CO=16 (no relu). Q -> P ----
    {
        const int Mc = B * 841;
        const int Mv = B * 625;
        ushort_t* Xhi = (ushort_t*)P;
        ushort_t* Xlo = Xhi + (size_t)(Mc + 2048) * 32;
        convert_nhwc<32, 841><<<CEILDIV(Mc, 256), blk, 0, stream>>>(Q, Xhi, Xlo, Mc);
        wprep<32, 25, 25, 64, 50><<<CEILDIV(25 * 64 * 32, 256), blk, 0, stream>>>(ow[2], WBhi, WBlo);
        conv_mfma<32, 5, 29, 29, 25, 25, 50, 4, 4, 25><<<dim3(CEILDIV(Mv, 256), 1), blk, 0, stream>>>(Xhi, Xlo, WBhi, WBlo, ob[2], OFF, Mv);
        wprep_d<32, 25, 28, 16, 16><<<CEILDIV(4 * 28 * 16 * 8, 256), blk, 0, stream>>>(w[2], WDhi, WDlo);
        deform_mfma<5, 32, 16, 29, 29, 25, 25, false, 8, 28><<<dim3(B * 5), dim3(512), 0, stream>>>(Q, OFF, WDhi, WDlo, bi[2], P);
    }
    // ---- stage 4: CI=16 K=7 25x25->19x19 OC(off)=98 CO=16. P -> Q ----
    {
        const int Mc = B * 625;
        const int Mv = B * 361;
        ushort_t* Xhi = (ushort_t*)Q;
        ushort_t* Xlo = Xhi + (size_t)(Mc + 2048) * 16;
        convert_nhwc<16, 625><<<CEILDIV(Mc, 256), blk, 0, stream>>>(P, Xhi, Xlo, Mc);
        wprep<16, 49, 50, 112, 98><<<CEILDIV(50 * 112 * 16, 256), blk, 0, stream>>>(ow[3], WBhi, WBlo);
        conv_mfma<16, 7, 25, 25, 19, 19, 98, 7, 4, 25><<<dim3(CEILDIV(Mv, 256), 2), blk, 0, stream>>>(Xhi, Xlo, WBhi, WBlo, ob[3], OFF, Mv);
        wprep_d<16, 49, 52, 16, 16><<<CEILDIV(2 * 52 * 16 * 8, 256), blk, 0, stream>>>(w[3], WDhi, WDlo);
        deform_mfma<7, 16, 16, 25, 25, 19, 19, true, 8, 52><<<dim3(B * 3), dim3(512), 0, stream>>>(P, OFF, WDhi, WDlo, bi[3], Q);
    }
    // ---- stage 5: CI=16 K=5 19x19->15x15 OC(off)=50 CO=8. Q -> P ----
    {
        const int Mc = B * 361;
        const int Mv = B * 225;
        ushort_t* Xhi = (ushort_t*)P;
        ushort_t* Xlo = Xhi + (size_t)(Mc + 2048) * 16;
        convert_nhwc<16, 361><<<CEILDIV(Mc, 256), blk, 0, stream>>>(Q, Xhi, Xlo, Mc);
        wprep<16, 25, 26, 64, 50><<<CEILDIV(26 * 64 * 16, 256), blk, 0, stream>>>(ow[4], WBhi, WBlo);
        conv_mfma<16, 5, 19, 19, 15, 15, 50, 4, 4, 13><<<dim3(CEILDIV(Mv, 256), 1), blk, 0, stream>>>(Xhi, Xlo, WBhi, WBlo, ob[4], OFF, Mv);
        wprep_d<16, 25, 28, 16, 8><<<CEILDIV(2 * 28 * 16 * 8, 256), blk, 0, stream>>>(w[4], WDhi, WDlo);
        deform_mfma<5, 16, 8, 19, 19, 15, 15, true, 4, 28><<<dim3(B * 4), dim3(256), 0, stream>>>(Q, OFF, WDhi, WDlo, bi[4], P);
    }
    // ---- stage 6: CI=8 K=3 15x15->13x13 CO=4. P -> Q ----
    conv_tile<3, 8, 6, 18, 15, 15, 13, 13, 4><<<GRIDT(13, 13, 4, 3), blk, 0, stream>>>(P, ow[5], ob[5], OFF);
    deform_lds<3, 8, 4, 15, 15, 13, 13, true, 8, 12, 192, 1><<<dim3(B), dim3(192), 0, stream>>>(P, OFF, w[5], bi[5], Q);

    // ---- FC head (reads Q = 512 x 4 x 13 x 13) ----
    wtrans<676, 256><<<CEILDIV(676 * 256, 256), blk, 0, stream>>>(fc1w, WT1);
    wtrans<256, 10><<<CEILDIV(256 * 10, 256), blk, 0, stream>>>(fc2w, WT2);
    fc_t<676, 256, true><<<dim3(CEILDIV(B * 256, 256)), blk, 0, stream>>>(Q, WT1, fc1b, Z, B);
    fc_t<256, 10, false><<<dim3(CEILDIV(B * 10, 256)), blk, 0, stream>>>(Z, WT2, fc2b, out, B);

    #undef GRIDT
    #undef CEILDIV
}

// Round 14
// 1004.695 us; speedup vs baseline: 1.0021x; 1.0021x over previous
//
#include <hip/hip_runtime.h>

typedef __attribute__((ext_vector_type(8))) short bf16x8;
typedef __attribute__((ext_vector_type(4))) float f32x4;
typedef unsigned short ushort_t;

__device__ inline ushort_t bf16_trunc(float f) { return (ushort_t)(__float_as_uint(f) >> 16); }
__device__ inline float bf16_to_f(ushort_t u) { return __uint_as_float(((unsigned int)u) << 16); }

// ---------------------------------------------------------------------------
// Weight prep for conv_mfma: OIHW fp32 -> [kk][n][ci] hi/lo, zero-padded.
// ---------------------------------------------------------------------------
template<int CI, int KK, int KKPAD, int NPAD, int OC>
__global__ __launch_bounds__(256)
void wprep(const float* __restrict__ w, ushort_t* __restrict__ bhi, ushort_t* __restrict__ blo)
{
    const int idx = blockIdx.x * 256 + threadIdx.x;
    if (idx >= KKPAD * NPAD * CI) return;
    const int kk  = idx / (NPAD * CI);
    const int rem = idx - kk * (NPAD * CI);
    const int n   = rem / CI;
    const int ci  = rem - n * CI;
    const float v = (kk < KK && n < OC) ? w[((size_t)n * CI + ci) * KK + kk] : 0.f;
    const ushort_t h = bf16_trunc(v);
    bhi[idx] = h;
    blo[idx] = bf16_trunc(v - bf16_to_f(h));
}

// ---------------------------------------------------------------------------
// Weight prep for deform_mfma: pack [kslot = pass*TPAD+tap][n][j=ci_in_pass].
// ---------------------------------------------------------------------------
template<int CI, int KK, int TPAD, int NPAD, int OC>
__global__ __launch_bounds__(256)
void wprep_d(const float* __restrict__ w, ushort_t* __restrict__ bhi, ushort_t* __restrict__ blo)
{
    constexpr int NPASS = (CI + 7) / 8;
    constexpr int TOTAL = NPASS * TPAD * NPAD * 8;
    const int idx = blockIdx.x * 256 + threadIdx.x;
    if (idx >= TOTAL) return;
    const int j     = idx & 7;
    const int n     = (idx >> 3) % NPAD;
    const int kslot = (idx >> 3) / NPAD;
    const int pass  = kslot / TPAD;
    const int tap   = kslot - pass * TPAD;
    const int ci    = pass * 8 + j;
    const float v = (tap < KK && n < OC && ci < CI) ? w[((size_t)n * CI + ci) * KK + tap] : 0.f;
    const ushort_t h = bf16_trunc(v);
    bhi[idx] = h;
    blo[idx] = bf16_trunc(v - bf16_to_f(h));
}

// ---------------------------------------------------------------------------
// MFMA implicit-im2col conv. Valid-m indexing + double-buffered LDS B slab.
// (unchanged from R12; input planes now produced by deform epilogues)
// ---------------------------------------------------------------------------
template<int CI, int K, int H, int W, int Ho, int Wo, int OC, int NTTOT, int NT0, int KSTEPS>
__global__ __launch_bounds__(256)
void conv_mfma(const ushort_t* __restrict__ Xhi, const ushort_t* __restrict__ Xlo,
               const ushort_t* __restrict__ Bhi, const ushort_t* __restrict__ Blo,
               const float* __restrict__ bias, float* __restrict__ out, int Mtotal)
{
    constexpr int NPAD = NTTOT * 16;
    constexpr int HW   = H * W;
    constexpr int HoWo = Ho * Wo;
    constexpr int TKS  = 32 / CI;
    constexpr int ROWS = TKS * NT0 * 16;
    constexpr int BSTR = CI + 8;
    constexpr int CH8  = CI / 8;
    constexpr int CHUNKS = ROWS * CH8;

    __shared__ __align__(16) ushort_t sBh[2][ROWS * BSTR];
    __shared__ __align__(16) ushort_t sBl[2][ROWS * BSTR];

    const int tid  = threadIdx.x;
    const int lane = tid & 63;
    const int wid  = tid >> 6;
    const int col  = lane & 15;
    const int quad = lane >> 4;

    const int mBase  = blockIdx.x * 256 + wid * 64;
    const int ntBase = blockIdx.y * NT0;

    int aBase[4];
#pragma unroll
    for (int mt = 0; mt < 4; ++mt) {
        int mm = mBase + mt * 16 + col;
        if (mm >= Mtotal) mm = Mtotal - 1;
        const int b   = mm / HoWo;
        const int pos = mm - b * HoWo;
        const int oy  = pos / Wo;
        const int ox  = pos - oy * Wo;
        aBase[mt] = (b * HW + oy * W + ox) * CI;
    }

    f32x4 acc[4][NT0];
#pragma unroll
    for (int mt = 0; mt < 4; ++mt)
#pragma unroll
        for (int nt = 0; nt < NT0; ++nt) acc[mt][nt] = (f32x4){0.f, 0.f, 0.f, 0.f};

    auto loadSlab = [&](int ks, int buf) {
        const int tap0 = ks * TKS;
        for (int i = tid; i < CHUNKS; i += 256) {
            const int row = i / CH8;
            const int c8  = i - row * CH8;
            const int t   = row / (NT0 * 16);
            const int nn  = row - t * (NT0 * 16);
            int n = ntBase * 16 + nn;
            if (n > NPAD - 1) n = NPAD - 1;
            const int g = ((tap0 + t) * NPAD + n) * CI + c8 * 8;
            *(bf16x8*)(sBh[buf] + row * BSTR + c8 * 8) = *(const bf16x8*)(Bhi + g);
            *(bf16x8*)(sBl[buf] + row * BSTR + c8 * 8) = *(const bf16x8*)(Blo + g);
        }
    };

    loadSlab(0, 0);
    __syncthreads();

#pragma unroll
    for (int ks = 0; ks < KSTEPS; ++ks) {
        if (ks + 1 < KSTEPS) loadSlab(ks + 1, (ks + 1) & 1);

        const int k0   = ks * 32 + quad * 8;
        const int tap  = k0 / CI;
        const int tloc = tap - ks * TKS;
        const int ci   = k0 - tap * CI;
        const int dkk  = (tap / K) * W + (tap - (tap / K) * K);

        bf16x8 ah[4], al[4];
#pragma unroll
        for (int mt = 0; mt < 4; ++mt) {
            const int aoff = aBase[mt] + dkk * CI + ci;
            ah[mt] = *(const bf16x8*)(Xhi + aoff);
            al[mt] = *(const bf16x8*)(Xlo + aoff);
        }
        const ushort_t* __restrict__ bhp = sBh[ks & 1];
        const ushort_t* __restrict__ blp = sBl[ks & 1];
#pragma unroll
        for (int nt = 0; nt < NT0; ++nt) {
            const int ntg = ntBase + nt;
            if (ntg < NTTOT) {
                const int lrow = ((tloc * NT0 + nt) * 16 + col) * BSTR + ci;
                const bf16x8 bh = *(const bf16x8*)(bhp + lrow);
                const bf16x8 bl = *(const bf16x8*)(blp + lrow);
#pragma unroll
                for (int mt = 0; mt < 4; ++mt) {
                    acc[mt][nt] = __builtin_amdgcn_mfma_f32_16x16x32_bf16(ah[mt], bh, acc[mt][nt], 0, 0, 0);
                    acc[mt][nt] = __builtin_amdgcn_mfma_f32_16x16x32_bf16(al[mt], bh, acc[mt][nt], 0, 0, 0);
                    acc[mt][nt] = __builtin_amdgcn_mfma_f32_16x16x32_bf16(ah[mt], bl, acc[mt][nt], 0, 0, 0);
                }
            }
        }
        __syncthreads();
    }

#pragma unroll
    for (int mt = 0; mt < 4; ++mt) {
#pragma unroll
        for (int nt = 0; nt < NT0; ++nt) {
            const int ntg = ntBase + nt;
            const int n   = ntg * 16 + col;
            if (ntg < NTTOT && n < OC) {
                const float bv = bias[n];
#pragma unroll
                for (int r = 0; r < 4; ++r) {
                    const int m = mBase + mt * 16 + quad * 4 + r;
                    if (m < Mtotal) {
                        const int b   = m / HoWo;
                        const int pos = m - b * HoWo;
                        out[((size_t)b * OC + n) * HoWo + pos] = acc[mt][nt][r] + bv;
                    }
                }
            }
        }
    }
}

// ---------------------------------------------------------------------------
// MFMA deformable conv (stages 2-5). R12 stride-12 LDS tile (R13 swizzle
// reverted). Input is NHWC bf16 hi/lo planes (reconstructed into the fp32
// tile at load); epilogue writes either NHWC hi/lo planes (OUTPL=true, feeds
// next stage's conv/deform) or fp32 NCHW (stage 5 -> stage 6).
// ---------------------------------------------------------------------------
template<int K, int CI, int CO, int H, int W, int Ho, int Wo, bool RELU,
         int MT, int TPAD, bool OUTPL>
__global__ __launch_bounds__(MT * 64)
void deform_mfma(const ushort_t* __restrict__ Xhi, const ushort_t* __restrict__ Xlo,
                 const float* __restrict__ off,
                 const ushort_t* __restrict__ Bph, const ushort_t* __restrict__ Bpl,
                 const float* __restrict__ bias,
                 float* __restrict__ outF, ushort_t* __restrict__ oHi, ushort_t* __restrict__ oLo)
{
    constexpr int KK     = K * K;
    constexpr int HW     = H * W;
    constexpr int HoWo   = Ho * Wo;
    constexpr int NPASS  = CI / 8;
    constexpr int NT     = (CO + 15) / 16;
    constexpr int NPAD   = NT * 16;
    constexpr int STRIDE = 12;
    constexpr int nMB    = (HoWo + MT * 16 - 1) / (MT * 16);
    constexpr int THREADS = MT * 64;
    __shared__ __align__(16) float tile[HW * STRIDE];

    const int b    = blockIdx.x / nMB;
    const int mb   = blockIdx.x - b * nMB;
    const int tid  = threadIdx.x;
    const int wid  = tid >> 6;
    const int lane = tid & 63;
    const int col  = lane & 15;
    const int quad = lane >> 4;

    const int pixel0 = (mb * MT + wid) * 16;
    const int s      = pixel0 + col;
    const bool am    = (s < HoWo);
    const int oy = s / Wo, ox = s - oy * Wo;

    const float* offB = off + (size_t)b * 2 * KK * HoWo;

    f32x4 acc[NT];
#pragma unroll
    for (int nt = 0; nt < NT; ++nt) acc[nt] = (f32x4){0.f, 0.f, 0.f, 0.f};

    for (int pass = 0; pass < NPASS; ++pass) {
        const int cbase = pass * 8;
        __syncthreads();
        for (int pos = tid; pos < HW; pos += THREADS) {
            const size_t g = ((size_t)b * HW + pos) * CI + cbase;
            const bf16x8 h8 = *(const bf16x8*)(Xhi + g);
            const bf16x8 l8 = *(const bf16x8*)(Xlo + g);
#pragma unroll
            for (int c = 0; c < 8; ++c)
                tile[pos * STRIDE + c] = bf16_to_f((ushort_t)h8[c]) + bf16_to_f((ushort_t)l8[c]);
        }
        __syncthreads();

#pragma unroll
        for (int tg = 0; tg < TPAD / 4; ++tg) {
            const int tap = tg * 4 + quad;
            bf16x8 ahi = (bf16x8){0,0,0,0,0,0,0,0};
            bf16x8 alo = (bf16x8){0,0,0,0,0,0,0,0};

            if (am && tap < KK) {
                const float dy = offB[(size_t)(2 * tap + 0) * HoWo + s];
                const float dx = offB[(size_t)(2 * tap + 1) * HoWo + s];
                const float py = (float)(tap / K + oy) + dy;
                const float px = (float)(tap % K + ox) + dx;
                const float y0f = floorf(py), x0f = floorf(px);
                const float wy = py - y0f, wx = px - x0f;
                const int y0 = (int)y0f, x0 = (int)x0f;
                const int y1 = y0 + 1,   x1 = x0 + 1;

                const float m00 = (y0 >= 0 && y0 < H && x0 >= 0 && x0 < W) ? 1.f : 0.f;
                const float m01 = (y0 >= 0 && y0 < H && x1 >= 0 && x1 < W) ? 1.f : 0.f;
                const float m10 = (y1 >= 0 && y1 < H && x0 >= 0 && x0 < W) ? 1.f : 0.f;
                const float m11 = (y1 >= 0 && y1 < H && x1 >= 0 && x1 < W) ? 1.f : 0.f;

                const float w00 = (1.f - wy) * (1.f - wx) * m00;
                const float w01 = (1.f - wy) * wx         * m01;
                const float w10 = wy         * (1.f - wx) * m10;
                const float w11 = wy         * wx         * m11;

                const int y0c = min(max(y0, 0), H - 1), y1c = min(max(y1, 0), H - 1);
                const int x0c = min(max(x0, 0), W - 1), x1c = min(max(x1, 0), W - 1);
                const int i00 = (y0c * W + x0c) * STRIDE;
                const int i01 = (y0c * W + x1c) * STRIDE;
                const int i10 = (y1c * W + x0c) * STRIDE;
                const int i11 = (y1c * W + x1c) * STRIDE;

                float v00[8], v01[8], v10[8], v11[8];
                *(f32x4*)(v00) = *(const f32x4*)(tile + i00); *(f32x4*)(v00 + 4) = *(const f32x4*)(tile + i00 + 4);
                *(f32x4*)(v01) = *(const f32x4*)(tile + i01); *(f32x4*)(v01 + 4) = *(const f32x4*)(tile + i01 + 4);
                *(f32x4*)(v10) = *(const f32x4*)(tile + i10); *(f32x4*)(v10 + 4) = *(const f32x4*)(tile + i10 + 4);
                *(f32x4*)(v11) = *(const f32x4*)(tile + i11); *(f32x4*)(v11 + 4) = *(const f32x4*)(tile + i11 + 4);
#pragma unroll
                for (int j = 0; j < 8; ++j) {
                    const float sv = fmaf(v11[j], w11, fmaf(v10[j], w10,
                                     fmaf(v01[j], w01, v00[j] * w00)));
                    const ushort_t h = bf16_trunc(sv);
                    ahi[j] = (short)h;
                    alo[j] = (short)bf16_trunc(sv - bf16_to_f(h));
                }
            }

            const size_t kslot = (size_t)(pass * TPAD + tap);
#pragma unroll
            for (int nt = 0; nt < NT; ++nt) {
                const bf16x8 bh = *(const bf16x8*)(Bph + (kslot * NPAD + nt * 16 + col) * 8);
                const bf16x8 bl = *(const bf16x8*)(Bpl + (kslot * NPAD + nt * 16 + col) * 8);
                acc[nt] = __builtin_amdgcn_mfma_f32_16x16x32_bf16(ahi, bh, acc[nt], 0, 0, 0);
                acc[nt] = __builtin_amdgcn_mfma_f32_16x16x32_bf16(alo, bh, acc[nt], 0, 0, 0);
                acc[nt] = __builtin_amdgcn_mfma_f32_16x16x32_bf16(ahi, bl, acc[nt], 0, 0, 0);
            }
        }
    }

#pragma unroll
    for (int nt = 0; nt < NT; ++nt) {
        const int n = nt * 16 + col;
        if (n < CO) {
            const float bv = bias[n];
#pragma unroll
            for (int r = 0; r < 4; ++r) {
                const int m = pixel0 + quad * 4 + r;
                if (m < HoWo) {
                    float v = acc[nt][r] + bv;
                    if (RELU) v = fmaxf(v, 0.f);
                    if (OUTPL) {
                        const size_t o = ((size_t)b * HoWo + m) * CO + n;
                        const ushort_t h = bf16_trunc(v);
                        oHi[o] = h;
                        oLo[o] = bf16_trunc(v - bf16_to_f(h));
                    } else {
                        outF[((size_t)b * CO + n) * HoWo + m] = v;
                    }
                }
            }
        }
    }
}

// ---------------------------------------------------------------------------
// Scalar LDS deform (stages 1 and 6). Reads fp32 NCHW. Epilogue writes
// NHWC hi/lo planes (OUTPL, stage 1) or fp32 NCHW (stage 6).
// ---------------------------------------------------------------------------
template<int K, int CI, int CO, int H, int W, int Ho, int Wo, bool RELU,
         int CSPLIT, int STRIDE, int THREADS, int SPLIT, bool OUTPL>
__global__ __launch_bounds__(THREADS)
void deform_lds(const float* __restrict__ x, const float* __restrict__ off,
                const float* __restrict__ w, const float* __restrict__ bias,
                float* __restrict__ outF, ushort_t* __restrict__ oHi, ushort_t* __restrict__ oLo)
{
    constexpr int KK    = K * K;
    constexpr int HW    = H * W;
    constexpr int HoWo  = Ho * Wo;
    constexpr int NPASS = CI / CSPLIT;
    constexpr int CHUNK = (HoWo + SPLIT - 1) / SPLIT;
    static_assert(CHUNK <= THREADS, "chunk must fit in one block");
    __shared__ __align__(16) float tile[HW * STRIDE];

    const int b   = blockIdx.x / SPLIT;
    const int sp  = blockIdx.x - b * SPLIT;
    const int tid = threadIdx.x;
    const int s   = sp * CHUNK + tid;
    const bool active = (tid < CHUNK) && (s < HoWo);

    const int oy = s / Wo, ox = s - oy * Wo;
    const float* offp = off + ((size_t)b * 2 * KK) * HoWo + s;

    float acc[CO];
#pragma unroll
    for (int o = 0; o < CO; ++o) acc[o] = 0.f;

    for (int pass = 0; pass < NPASS; ++pass) {
        const int cbase = pass * CSPLIT;
        __syncthreads();
        for (int pos = tid; pos < HW; pos += THREADS) {
#pragma unroll
            for (int c = 0; c < CSPLIT; ++c)
                tile[pos * STRIDE + c] = x[((size_t)b * CI + (cbase + c)) * HW + pos];
        }
        __syncthreads();

        if (active) {
            for (int kk = 0; kk < KK; ++kk) {
                const float dy = offp[(size_t)(2 * kk + 0) * HoWo];
                const float dx = offp[(size_t)(2 * kk + 1) * HoWo];
                const float py = (float)(kk / K + oy) + dy;
                const float px = (float)(kk % K + ox) + dx;
                const float y0f = floorf(py), x0f = floorf(px);
                const float wy = py - y0f, wx = px - x0f;
                const int y0 = (int)y0f, x0 = (int)x0f;
                const int y1 = y0 + 1,   x1 = x0 + 1;

                const float m00 = (y0 >= 0 && y0 < H && x0 >= 0 && x0 < W) ? 1.f : 0.f;
                const float m01 = (y0 >= 0 && y0 < H && x1 >= 0 && x1 < W) ? 1.f : 0.f;
                const float m10 = (y1 >= 0 && y1 < H && x0 >= 0 && x0 < W) ? 1.f : 0.f;
                const float m11 = (y1 >= 0 && y1 < H && x1 >= 0 && x1 < W) ? 1.f : 0.f;

                const float w00 = (1.f - wy) * (1.f - wx) * m00;
                const float w01 = (1.f - wy) * wx         * m01;
                const float w10 = wy         * (1.f - wx) * m10;
                const float w11 = wy         * wx         * m11;

                const int y0c = min(max(y0, 0), H - 1), y1c = min(max(y1, 0), H - 1);
                const int x0c = min(max(x0, 0), W - 1), x1c = min(max(x1, 0), W - 1);
                const int i00 = (y0c * W + x0c) * STRIDE;
                const int i01 = (y0c * W + x1c) * STRIDE;
                const int i10 = (y1c * W + x0c) * STRIDE;
                const int i11 = (y1c * W + x1c) * STRIDE;

                if constexpr (CSPLIT % 4 == 0) {
#pragma unroll
                    for (int cg = 0; cg < CSPLIT; cg += 4) {
                        const f32x4 v00 = *(const f32x4*)(tile + i00 + cg);
                        const f32x4 v01 = *(const f32x4*)(tile + i01 + cg);
                        const f32x4 v10 = *(const f32x4*)(tile + i10 + cg);
                        const f32x4 v11 = *(const f32x4*)(tile + i11 + cg);
#pragma unroll
                        for (int j = 0; j < 4; ++j) {
                            const float sv = fmaf(v11[j], w11, fmaf(v10[j], w10,
                                             fmaf(v01[j], w01, v00[j] * w00)));
#pragma unroll
                            for (int o = 0; o < CO; ++o)
                                acc[o] = fmaf(sv, w[(size_t)(o * CI + cbase + cg + j) * KK + kk], acc[o]);
                        }
                    }
                } else {
                    const float sv = fmaf(tile[i11], w11, fmaf(tile[i10], w10,
                                     fmaf(tile[i01], w01, tile[i00] * w00)));
#pragma unroll
                    for (int o = 0; o < CO; ++o)
                        acc[o] = fmaf(sv, w[(size_t)(o * CI + cbase) * KK + kk], acc[o]);
                }
            }
        }
    }

    if (active) {
#pragma unroll
        for (int o = 0; o < CO; ++o) {
            float v = acc[o] + bias[o];
            if (RELU) v = fmaxf(v, 0.f);
            if (OUTPL) {
                const size_t oi = ((size_t)b * HoWo + s) * CO + o;
                const ushort_t h = bf16_trunc(v);
                oHi[oi] = h;
                oLo[oi] = bf16_trunc(v - bf16_to_f(h));
            } else {
                outF[((size_t)b * CO + o) * HoWo + s] = v;
            }
        }
    }
}

// ---------------------------------------------------------------------------
// Register-tiled direct VALID conv (stages 1 and 6 offset convs).
// ---------------------------------------------------------------------------
template<int K, int CI, int NOC, int OC, int H, int W, int Ho, int Wo, int PIX>
__global__ __launch_bounds__(256)
void conv_tile(const float* __restrict__ x, const float* __restrict__ w,
               const float* __restrict__ bias, float* __restrict__ out)
{
    constexpr int KK   = K * K;
    constexpr int HoWo = Ho * Wo;
    constexpr int WoG  = (Wo + PIX - 1) / PIX;
    constexpr int G    = Ho * WoG;
    constexpr int XV   = PIX + K - 1;

    const int oc0   = blockIdx.y * NOC;
    const int g_all = blockIdx.x * 256 + threadIdx.x;
    const int b     = g_all / G;
    const int g     = g_all - b * G;
    const int oy    = g / WoG;
    const int ox0   = (g - oy * WoG) * PIX;

    const float* xbp = x + (b * CI) * (H * W) + oy * W + ox0;
    const float* wp  = w + oc0 * (CI * KK);

    float acc[PIX][NOC];
#pragma unroll
    for (int p = 0; p < PIX; ++p)
#pragma unroll
        for (int j = 0; j < NOC; ++j) acc[p][j] = bias[oc0 + j];

    const int lim = W - 1 - ox0;

    for (int ci = 0; ci < CI; ++ci) {
        const float* xc = xbp + ci * (H * W);
#pragma unroll
        for (int ky = 0; ky < K; ++ky) {
            float xv[XV];
#pragma unroll
            for (int i = 0; i < XV; ++i) {
                const int off = (i <= lim) ? i : lim;
                xv[i] = xc[ky * W + off];
            }
#pragma unroll
            for (int kx = 0; kx < K; ++kx) {
#pragma unroll
                for (int p = 0; p < PIX; ++p) {
                    const float v = xv[p + kx];
#pragma unroll
                    for (int j = 0; j < NOC; ++j)
                        acc[p][j] = fmaf(v, wp[j * (CI * KK) + ci * KK + ky * K + kx], acc[p][j]);
                }
            }
        }
    }

    float* op = out + (b * OC + oc0) * HoWo + oy * Wo + ox0;
#pragma unroll
    for (int p = 0; p < PIX; ++p) {
        if (ox0 + p < Wo) {
#pragma unroll
            for (int j = 0; j < NOC; ++j) op[j * HoWo + p] = acc[p][j];
        }
    }
}

// ---------------------------------------------------------------------------
// FC weight transpose + coalesced FC (from R12).
// ---------------------------------------------------------------------------
template<int IN, int OUT>
__global__ __launch_bounds__(256)
void wtrans(const float* __restrict__ w, float* __restrict__ wt)
{
    const int idx = blockIdx.x * 256 + threadIdx.x;
    if (idx >= IN * OUT) return;
    const int i = idx / OUT, j = idx - i * OUT;
    wt[idx] = w[(size_t)j * IN + i];
}

template<int IN, int OUT, bool RELU>
__global__ __launch_bounds__(256)
void fc_t(const float* __restrict__ h, const float* __restrict__ wt,
          const float* __restrict__ bias, float* __restrict__ out, int B)
{
    const int idx = blockIdx.x * 256 + threadIdx.x;
    if (idx >= B * OUT) return;
    const int b = idx / OUT;
    const int j = idx - b * OUT;
    const float* hb = h + (size_t)b * IN;
    float acc = bias[j];
#pragma unroll 4
    for (int i = 0; i < IN; ++i)
        acc = fmaf(hb[i], wt[(size_t)i * OUT + j], acc);
    if (RELU) acc = fmaxf(acc, 0.f);
    out[idx] = acc;
}

// ---------------------------------------------------------------------------
// Dataflow: activations live as NHWC bf16 hi/lo planes between stages 1-5
// (deform epilogues produce them; conv_mfma and deform tile-loads consume).
// Stage-5 deform writes fp32 NCHW for the scalar stage-6 path.
// Plane regions ping-pong between P and Q (max 13.84M floats < 14M).
// ---------------------------------------------------------------------------
extern "C" void kernel_launch(void* const* d_in, const int* in_sizes, int n_in,
                              void* d_out, int out_size, void* d_ws, size_t ws_size,
                              hipStream_t stream)
{
    const int B = 512;
    const float* x = (const float*)d_in[0];
    const float *ow[6], *ob[6], *w[6], *bi[6];
    for (int i = 0; i < 6; ++i) {
        ow[i] = (const float*)d_in[1 + 4 * i];
        ob[i] = (const float*)d_in[2 + 4 * i];
        w[i]  = (const float*)d_in[3 + 4 * i];
        bi[i] = (const float*)d_in[4 + 4 * i];
    }
    const float* fc1w = (const float*)d_in[25];
    const float* fc1b = (const float*)d_in[26];
    const float* fc2w = (const float*)d_in[27];
    const float* fc2b = (const float*)d_in[28];
    float* out = (float*)d_out;

    float* P   = (float*)d_ws;        // 14M floats
    float* Q   = P  + 14000000;       // 14M floats
    float* OFF = Q  + 14000000;       // 18.2M floats
    float* Z   = OFF + 18200000;      // fc intermediate
    ushort_t* WBhi = (ushort_t*)(Z + 200000);   // conv_mfma weights
    ushort_t* WBlo = WBhi + 200000;
    ushort_t* WDhi = WBlo + 200000;             // deform_mfma weights
    ushort_t* WDlo = WDhi + 200000;
    float* WT1 = (float*)(WDlo + 200000);       // fc1 wT
    float* WT2 = WT1 + 173056;                  // fc2 wT

    const dim3 blk(256);
    #define GRIDT(Ho, Wo, PIX, NG) dim3((B * (Ho) * (((Wo) + (PIX) - 1) / (PIX)) + 255) / 256, (NG), 1)
    #define CEILDIV(a, b) (((a) + (b) - 1) / (b))

    // plane regions
    ushort_t* PL2h = (ushort_t*)Q;  ushort_t* PL2l = PL2h + (size_t)(B * 961 + 2048) * 16;  // stage-2 input (CI=16)
    ushort_t* PL3h = (ushort_t*)P;  ushort_t* PL3l = PL3h + (size_t)(B * 841 + 2048) * 32;  // stage-3 input (CI=32)
    ushort_t* PL4h = (ushort_t*)Q;  ushort_t* PL4l = PL4h + (size_t)(B * 625 + 2048) * 16;  // stage-4 input (CI=16)
    ushort_t* PL5h = (ushort_t*)P;  ushort_t* PL5l = PL5h + (size_t)(B * 361 + 2048) * 16;  // stage-5 input (CI=16)

    // ---- stage 1: input x (CI=1). conv_tile -> OFF; deform_lds -> PL2 ----
    conv_tile<3, 1, 6, 18, 33, 33, 31, 31, 4><<<GRIDT(31, 31, 4, 3), blk, 0, stream>>>(x, ow[0], ob[0], OFF);
    deform_lds<3, 1, 16, 33, 33, 31, 31, true, 1, 1, 512, 2, true><<<dim3(B * 2), dim3(512), 0, stream>>>(x, OFF, w[0], bi[0], nullptr, PL2h, PL2l);

    // ---- stage 2: CI=16 K=3 31x31->29x29 OC(off)=18 CO=32. PL2 -> PL3 ----
    {
        const int Mv = B * 841;
        wprep<16, 9, 10, 32, 18><<<CEILDIV(10 * 32 * 16, 256), blk, 0, stream>>>(ow[1], WBhi, WBlo);
        conv_mfma<16, 3, 31, 31, 29, 29, 18, 2, 2, 5><<<dim3(CEILDIV(Mv, 256), 1), blk, 0, stream>>>(PL2h, PL2l, WBhi, WBlo, ob[1], OFF, Mv);
        wprep_d<16, 9, 12, 32, 32><<<CEILDIV(2 * 12 * 32 * 8, 256), blk, 0, stream>>>(w[1], WDhi, WDlo);
        deform_mfma<3, 16, 32, 31, 31, 29, 29, true, 8, 12, true><<<dim3(B * 7), dim3(512), 0, stream>>>(PL2h, PL2l, OFF, WDhi, WDlo, bi[1], nullptr, PL3h, PL3l);
    }
    // ---- stage 3: CI=32 K=5 29x29->25x25 OC(off)=50 CO=16 (no relu). PL3 -> PL4 ----
    {
        const int Mv = B * 625;
        wprep<32, 25, 25, 64, 50><<<CEILDIV(25 * 64 * 32, 256), blk, 0, stream>>>(ow[2], WBhi, WBlo);
        conv_mfma<32, 5, 29, 29, 25, 25, 50, 4, 4, 25><<<dim3(CEILDIV(Mv, 256), 1), blk, 0, stream>>>(PL3h, PL3l, WBhi, WBlo, ob[2], OFF, Mv);
        wprep_d<32, 25, 28, 16, 16><<<CEILDIV(4 * 28 * 16 * 8, 256), blk, 0, stream>>>(w[2], WDhi, WDlo);
        deform_mfma<5, 32, 16, 29, 29, 25, 25, false, 8, 28, true><<<dim3(B * 5), dim3(512), 0, stream>>>(PL3h, PL3l, OFF, WDhi, WDlo, bi[2], nullptr, PL4h, PL4l);
    }
    // ---- stage 4: CI=16 K=7 25x25->19x19 OC(off)=98 CO=16. PL4 -> PL5 ----
    {
        const int Mv = B * 361;
        wprep<16, 49, 50, 112, 98><<<CEILDIV(50 * 112 * 16, 256), blk, 0, stream>>>(ow[3], WBhi, WBlo);
        conv_mfma<16, 7, 25, 25, 19, 19, 98, 7, 4, 25><<<dim3(CEILDIV(Mv, 256), 2), blk, 0, stream>>>(PL4h, PL4l, WBhi, WBlo, ob[3], OFF, Mv);
        wprep_d<16, 49, 52, 16, 16><<<CEILDIV(2 * 52 * 16 * 8, 256), blk, 0, stream>>>(w[3], WDhi, WDlo);
        deform_mfma<7, 16, 16, 25, 25, 19, 19, true, 8, 52, true><<<dim3(B * 3), dim3(512), 0, stream>>>(PL4h, PL4l, OFF, WDhi, WDlo, bi[3], nullptr, PL5h, PL5l);
    }
    // ---- stage 5: CI=16 K=5 19x19->15x15 OC(off)=50 CO=8. PL5 -> Q (fp32 NCHW) ----
    {
        const int Mv = B * 225;
        wprep<16, 25, 26, 64, 50><<<CEILDIV(26 * 64 * 16, 256), blk, 0, stream>>>(ow[4], WBhi, WBlo);
        conv_mfma<16, 5, 19, 19, 15, 15, 50, 4, 4, 13><<<dim3(CEILDIV(Mv, 256), 1), blk, 0, stream>>>(PL5h, PL5l, WBhi, WBlo, ob[4], OFF, Mv);
        wprep_d<16, 25, 28, 16, 8><<<CEILDIV(2 * 28 * 16 * 8, 256), blk, 0, stream>>>(w[4], WDhi, WDlo);
        deform_mfma<5, 16, 8, 19, 19, 15, 15, true, 4, 28, false><<<dim3(B * 4), dim3(256), 0, stream>>>(PL5h, PL5l, OFF, WDhi, WDlo, bi[4], Q, nullptr, nullptr);
    }
    // ---- stage 6: CI=8 K=3 15x15->13x13 CO=4. Q -> P (fp32 NCHW) ----
    conv_tile<3, 8, 6, 18, 15, 15, 13, 13, 4><<<GRIDT(13, 13, 4, 3), blk, 0, stream>>>(Q, ow[5], ob[5], OFF);
    deform_lds<3, 8, 4, 15, 15, 13, 13, true, 8, 12, 192, 1, false><<<dim3(B), dim3(192), 0, stream>>>(Q, OFF, w[5], bi[5], P, nullptr, nullptr);

    // ---- FC head (reads P = 512 x 4 x 13 x 13) ----
    wtrans<676, 256><<<CEILDIV(676 * 256, 256), blk, 0, stream>>>(fc1w, WT1);
    wtrans<256, 10><<<CEILDIV(256 * 10, 256), blk, 0, stream>>>(fc2w, WT2);
    fc_t<676, 256, true><<<dim3(CEILDIV(B * 256, 256)), blk, 0, stream>>>(P, WT1, fc1b, Z, B);
    fc_t<256, 10, false><<<dim3(CEILDIV(B * 10, 256)), blk, 0, stream>>>(Z, WT2, fc2b, out, B);

    #undef GRIDT
    #undef CEILDIV
}

// Round 15
// 900.057 us; speedup vs baseline: 1.1186x; 1.1163x over previous
//
#include <hip/hip_runtime.h>

typedef __attribute__((ext_vector_type(8))) short bf16x8;
typedef __attribute__((ext_vector_type(4))) float f32x4;
typedef unsigned short ushort_t;

__device__ inline ushort_t bf16_trunc(float f) { return (ushort_t)(__float_as_uint(f) >> 16); }
__device__ inline float bf16_to_f(ushort_t u) { return __uint_as_float(((unsigned int)u) << 16); }

// ---------------------------------------------------------------------------
// Weight prep for conv_mfma: OIHW fp32 -> [kk][n][ci] hi/lo, zero-padded.
// ---------------------------------------------------------------------------
template<int CI, int KK, int KKPAD, int NPAD, int OC>
__global__ __launch_bounds__(256)
void wprep(const float* __restrict__ w, ushort_t* __restrict__ bhi, ushort_t* __restrict__ blo)
{
    const int idx = blockIdx.x * 256 + threadIdx.x;
    if (idx >= KKPAD * NPAD * CI) return;
    const int kk  = idx / (NPAD * CI);
    const int rem = idx - kk * (NPAD * CI);
    const int n   = rem / CI;
    const int ci  = rem - n * CI;
    const float v = (kk < KK && n < OC) ? w[((size_t)n * CI + ci) * KK + kk] : 0.f;
    const ushort_t h = bf16_trunc(v);
    bhi[idx] = h;
    blo[idx] = bf16_trunc(v - bf16_to_f(h));
}

// ---------------------------------------------------------------------------
// Weight prep for deform_mfma: pack [kslot = pass*TPAD+tap][n][j=ci_in_pass].
// ---------------------------------------------------------------------------
template<int CI, int KK, int TPAD, int NPAD, int OC>
__global__ __launch_bounds__(256)
void wprep_d(const float* __restrict__ w, ushort_t* __restrict__ bhi, ushort_t* __restrict__ blo)
{
    constexpr int NPASS = (CI + 7) / 8;
    constexpr int TOTAL = NPASS * TPAD * NPAD * 8;
    const int idx = blockIdx.x * 256 + threadIdx.x;
    if (idx >= TOTAL) return;
    const int j     = idx & 7;
    const int n     = (idx >> 3) % NPAD;
    const int kslot = (idx >> 3) / NPAD;
    const int pass  = kslot / TPAD;
    const int tap   = kslot - pass * TPAD;
    const int ci    = pass * 8 + j;
    const float v = (tap < KK && n < OC && ci < CI) ? w[((size_t)n * CI + ci) * KK + tap] : 0.f;
    const ushort_t h = bf16_trunc(v);
    bhi[idx] = h;
    blo[idx] = bf16_trunc(v - bf16_to_f(h));
}

// ---------------------------------------------------------------------------
// MFMA implicit-im2col conv. Valid-m indexing + double-buffered LDS B slab.
// A-operand planes in channel-grouped layout [b][g=ci/8][pos][8]:
//   addr(m, tap, ci) = (b*NPASS*HW + pos + (ci/8)*HW + dkk) * 8
// Linear in dkk per (lane,ks); a lane's 8 channels always within one group.
// ---------------------------------------------------------------------------
template<int CI, int K, int H, int W, int Ho, int Wo, int OC, int NTTOT, int NT0, int KSTEPS>
__global__ __launch_bounds__(256)
void conv_mfma(const ushort_t* __restrict__ Xhi, const ushort_t* __restrict__ Xlo,
               const ushort_t* __restrict__ Bhi, const ushort_t* __restrict__ Blo,
               const float* __restrict__ bias, float* __restrict__ out, int Mtotal)
{
    constexpr int NPAD = NTTOT * 16;
    constexpr int HW   = H * W;
    constexpr int HoWo = Ho * Wo;
    constexpr int NPASS = CI / 8;
    constexpr int TKS  = 32 / CI;
    constexpr int ROWS = TKS * NT0 * 16;
    constexpr int BSTR = CI + 8;
    constexpr int CH8  = CI / 8;
    constexpr int CHUNKS = ROWS * CH8;

    __shared__ __align__(16) ushort_t sBh[2][ROWS * BSTR];
    __shared__ __align__(16) ushort_t sBl[2][ROWS * BSTR];

    const int tid  = threadIdx.x;
    const int lane = tid & 63;
    const int wid  = tid >> 6;
    const int col  = lane & 15;
    const int quad = lane >> 4;

    const int mBase  = blockIdx.x * 256 + wid * 64;
    const int ntBase = blockIdx.y * NT0;

    int aBase[4];   // b*NPASS*HW + pos (group-element units)
#pragma unroll
    for (int mt = 0; mt < 4; ++mt) {
        int mm = mBase + mt * 16 + col;
        if (mm >= Mtotal) mm = Mtotal - 1;
        const int b   = mm / HoWo;
        const int pos = mm - b * HoWo;
        const int oy  = pos / Wo;
        const int ox  = pos - oy * Wo;
        aBase[mt] = b * NPASS * HW + oy * W + ox;
    }

    f32x4 acc[4][NT0];
#pragma unroll
    for (int mt = 0; mt < 4; ++mt)
#pragma unroll
        for (int nt = 0; nt < NT0; ++nt) acc[mt][nt] = (f32x4){0.f, 0.f, 0.f, 0.f};

    auto loadSlab = [&](int ks, int buf) {
        const int tap0 = ks * TKS;
        for (int i = tid; i < CHUNKS; i += 256) {
            const int row = i / CH8;
            const int c8  = i - row * CH8;
            const int t   = row / (NT0 * 16);
            const int nn  = row - t * (NT0 * 16);
            int n = ntBase * 16 + nn;
            if (n > NPAD - 1) n = NPAD - 1;
            const int g = ((tap0 + t) * NPAD + n) * CI + c8 * 8;
            *(bf16x8*)(sBh[buf] + row * BSTR + c8 * 8) = *(const bf16x8*)(Bhi + g);
            *(bf16x8*)(sBl[buf] + row * BSTR + c8 * 8) = *(const bf16x8*)(Blo + g);
        }
    };

    loadSlab(0, 0);
    __syncthreads();

#pragma unroll
    for (int ks = 0; ks < KSTEPS; ++ks) {
        if (ks + 1 < KSTEPS) loadSlab(ks + 1, (ks + 1) & 1);

        const int k0   = ks * 32 + quad * 8;
        const int tap  = k0 / CI;
        const int tloc = tap - ks * TKS;
        const int ci   = k0 - tap * CI;
        const int g    = ci >> 3;
        const int dkk  = (tap / K) * W + (tap - (tap / K) * K);

        bf16x8 ah[4], al[4];
#pragma unroll
        for (int mt = 0; mt < 4; ++mt) {
            const size_t aoff = (size_t)(aBase[mt] + g * HW + dkk) * 8;
            ah[mt] = *(const bf16x8*)(Xhi + aoff);
            al[mt] = *(const bf16x8*)(Xlo + aoff);
        }
        const ushort_t* __restrict__ bhp = sBh[ks & 1];
        const ushort_t* __restrict__ blp = sBl[ks & 1];
#pragma unroll
        for (int nt = 0; nt < NT0; ++nt) {
            const int ntg = ntBase + nt;
            if (ntg < NTTOT) {
                const int lrow = ((tloc * NT0 + nt) * 16 + col) * BSTR + ci;
                const bf16x8 bh = *(const bf16x8*)(bhp + lrow);
                const bf16x8 bl = *(const bf16x8*)(blp + lrow);
#pragma unroll
                for (int mt = 0; mt < 4; ++mt) {
                    acc[mt][nt] = __builtin_amdgcn_mfma_f32_16x16x32_bf16(ah[mt], bh, acc[mt][nt], 0, 0, 0);
                    acc[mt][nt] = __builtin_amdgcn_mfma_f32_16x16x32_bf16(al[mt], bh, acc[mt][nt], 0, 0, 0);
                    acc[mt][nt] = __builtin_amdgcn_mfma_f32_16x16x32_bf16(ah[mt], bl, acc[mt][nt], 0, 0, 0);
                }
            }
        }
        __syncthreads();
    }

#pragma unroll
    for (int mt = 0; mt < 4; ++mt) {
#pragma unroll
        for (int nt = 0; nt < NT0; ++nt) {
            const int ntg = ntBase + nt;
            const int n   = ntg * 16 + col;
            if (ntg < NTTOT && n < OC) {
                const float bv = bias[n];
#pragma unroll
                for (int r = 0; r < 4; ++r) {
                    const int m = mBase + mt * 16 + quad * 4 + r;
                    if (m < Mtotal) {
                        const int b   = m / HoWo;
                        const int pos = m - b * HoWo;
                        out[((size_t)b * OC + n) * HoWo + pos] = acc[mt][nt][r] + bv;
                    }
                }
            }
        }
    }
}

// ---------------------------------------------------------------------------
// MFMA deformable conv (stages 2-5). Input planes channel-grouped: pass g's
// tile load reads contiguous 16B chunks (fully coalesced, 1/NPASS of data
// per pass). Epilogue writes grouped planes (OUTPL) or fp32 NCHW.
// ---------------------------------------------------------------------------
template<int K, int CI, int CO, int H, int W, int Ho, int Wo, bool RELU,
         int MT, int TPAD, bool OUTPL>
__global__ __launch_bounds__(MT * 64)
void deform_mfma(const ushort_t* __restrict__ Xhi, const ushort_t* __restrict__ Xlo,
                 const float* __restrict__ off,
                 const ushort_t* __restrict__ Bph, const ushort_t* __restrict__ Bpl,
                 const float* __restrict__ bias,
                 float* __restrict__ outF, ushort_t* __restrict__ oHi, ushort_t* __restrict__ oLo)
{
    constexpr int KK     = K * K;
    constexpr int HW     = H * W;
    constexpr int HoWo   = Ho * Wo;
    constexpr int NPASS  = CI / 8;
    constexpr int NPO    = CO / 8;
    constexpr int NT     = (CO + 15) / 16;
    constexpr int NPAD   = NT * 16;
    constexpr int STRIDE = 12;
    constexpr int nMB    = (HoWo + MT * 16 - 1) / (MT * 16);
    constexpr int THREADS = MT * 64;
    __shared__ __align__(16) float tile[HW * STRIDE];

    const int b    = blockIdx.x / nMB;
    const int mb   = blockIdx.x - b * nMB;
    const int tid  = threadIdx.x;
    const int wid  = tid >> 6;
    const int lane = tid & 63;
    const int col  = lane & 15;
    const int quad = lane >> 4;

    const int pixel0 = (mb * MT + wid) * 16;
    const int s      = pixel0 + col;
    const bool am    = (s < HoWo);
    const int oy = s / Wo, ox = s - oy * Wo;

    const float* offB = off + (size_t)b * 2 * KK * HoWo;

    f32x4 acc[NT];
#pragma unroll
    for (int nt = 0; nt < NT; ++nt) acc[nt] = (f32x4){0.f, 0.f, 0.f, 0.f};

    for (int pass = 0; pass < NPASS; ++pass) {
        __syncthreads();
        for (int pos = tid; pos < HW; pos += THREADS) {
            const size_t g = ((size_t)(b * NPASS + pass) * HW + pos) * 8;
            const bf16x8 h8 = *(const bf16x8*)(Xhi + g);
            const bf16x8 l8 = *(const bf16x8*)(Xlo + g);
#pragma unroll
            for (int c = 0; c < 8; ++c)
                tile[pos * STRIDE + c] = bf16_to_f((ushort_t)h8[c]) + bf16_to_f((ushort_t)l8[c]);
        }
        __syncthreads();

#pragma unroll
        for (int tg = 0; tg < TPAD / 4; ++tg) {
            const int tap = tg * 4 + quad;
            bf16x8 ahi = (bf16x8){0,0,0,0,0,0,0,0};
            bf16x8 alo = (bf16x8){0,0,0,0,0,0,0,0};

            if (am && tap < KK) {
                const float dy = offB[(size_t)(2 * tap + 0) * HoWo + s];
                const float dx = offB[(size_t)(2 * tap + 1) * HoWo + s];
                const float py = (float)(tap / K + oy) + dy;
                const float px = (float)(tap % K + ox) + dx;
                const float y0f = floorf(py), x0f = floorf(px);
                const float wy = py - y0f, wx = px - x0f;
                const int y0 = (int)y0f, x0 = (int)x0f;
                const int y1 = y0 + 1,   x1 = x0 + 1;

                const float m00 = (y0 >= 0 && y0 < H && x0 >= 0 && x0 < W) ? 1.f : 0.f;
                const float m01 = (y0 >= 0 && y0 < H && x1 >= 0 && x1 < W) ? 1.f : 0.f;
                const float m10 = (y1 >= 0 && y1 < H && x0 >= 0 && x0 < W) ? 1.f : 0.f;
                const float m11 = (y1 >= 0 && y1 < H && x1 >= 0 && x1 < W) ? 1.f : 0.f;

                const float w00 = (1.f - wy) * (1.f - wx) * m00;
                const float w01 = (1.f - wy) * wx         * m01;
                const float w10 = wy         * (1.f - wx) * m10;
                const float w11 = wy         * wx         * m11;

                const int y0c = min(max(y0, 0), H - 1), y1c = min(max(y1, 0), H - 1);
                const int x0c = min(max(x0, 0), W - 1), x1c = min(max(x1, 0), W - 1);
                const int i00 = (y0c * W + x0c) * STRIDE;
                const int i01 = (y0c * W + x1c) * STRIDE;
                const int i10 = (y1c * W + x0c) * STRIDE;
                const int i11 = (y1c * W + x1c) * STRIDE;

                float v00[8], v01[8], v10[8], v11[8];
                *(f32x4*)(v00) = *(const f32x4*)(tile + i00); *(f32x4*)(v00 + 4) = *(const f32x4*)(tile + i00 + 4);
                *(f32x4*)(v01) = *(const f32x4*)(tile + i01); *(f32x4*)(v01 + 4) = *(const f32x4*)(tile + i01 + 4);
                *(f32x4*)(v10) = *(const f32x4*)(tile + i10); *(f32x4*)(v10 + 4) = *(const f32x4*)(tile + i10 + 4);
                *(f32x4*)(v11) = *(const f32x4*)(tile + i11); *(f32x4*)(v11 + 4) = *(const f32x4*)(tile + i11 + 4);
#pragma unroll
                for (int j = 0; j < 8; ++j) {
                    const float sv = fmaf(v11[j], w11, fmaf(v10[j], w10,
                                     fmaf(v01[j], w01, v00[j] * w00)));
                    const ushort_t h = bf16_trunc(sv);
                    ahi[j] = (short)h;
                    alo[j] = (short)bf16_trunc(sv - bf16_to_f(h));
                }
            }

            const size_t kslot = (size_t)(pass * TPAD + tap);
#pragma unroll
            for (int nt = 0; nt < NT; ++nt) {
                const bf16x8 bh = *(const bf16x8*)(Bph + (kslot * NPAD + nt * 16 + col) * 8);
                const bf16x8 bl = *(const bf16x8*)(Bpl + (kslot * NPAD + nt * 16 + col) * 8);
                acc[nt] = __builtin_amdgcn_mfma_f32_16x16x32_bf16(ahi, bh, acc[nt], 0, 0, 0);
                acc[nt] = __builtin_amdgcn_mfma_f32_16x16x32_bf16(alo, bh, acc[nt], 0, 0, 0);
                acc[nt] = __builtin_amdgcn_mfma_f32_16x16x32_bf16(ahi, bl, acc[nt], 0, 0, 0);
            }
        }
    }

#pragma unroll
    for (int nt = 0; nt < NT; ++nt) {
        const int n = nt * 16 + col;
        if (n < CO) {
            const float bv = bias[n];
#pragma unroll
            for (int r = 0; r < 4; ++r) {
                const int m = pixel0 + quad * 4 + r;
                if (m < HoWo) {
                    float v = acc[nt][r] + bv;
                    if (RELU) v = fmaxf(v, 0.f);
                    if (OUTPL) {
                        const size_t o = (((size_t)b * NPO + (n >> 3)) * HoWo + m) * 8 + (n & 7);
                        const ushort_t h = bf16_trunc(v);
                        oHi[o] = h;
                        oLo[o] = bf16_trunc(v - bf16_to_f(h));
                    } else {
                        outF[((size_t)b * CO + n) * HoWo + m] = v;
                    }
                }
            }
        }
    }
}

// ---------------------------------------------------------------------------
// Scalar LDS deform (stages 1 and 6). Reads fp32 NCHW. Epilogue writes
// grouped planes (OUTPL, stage 1) or fp32 NCHW (stage 6).
// ---------------------------------------------------------------------------
template<int K, int CI, int CO, int H, int W, int Ho, int Wo, bool RELU,
         int CSPLIT, int STRIDE, int THREADS, int SPLIT, bool OUTPL>
__global__ __launch_bounds__(THREADS)
void deform_lds(const float* __restrict__ x, const float* __restrict__ off,
                const float* __restrict__ w, const float* __restrict__ bias,
                float* __restrict__ outF, ushort_t* __restrict__ oHi, ushort_t* __restrict__ oLo)
{
    constexpr int KK    = K * K;
    constexpr int HW    = H * W;
    constexpr int HoWo  = Ho * Wo;
    constexpr int NPASS = CI / CSPLIT;
    constexpr int NPO   = (CO + 7) / 8;
    constexpr int CHUNK = (HoWo + SPLIT - 1) / SPLIT;
    static_assert(CHUNK <= THREADS, "chunk must fit in one block");
    __shared__ __align__(16) float tile[HW * STRIDE];

    const int b   = blockIdx.x / SPLIT;
    const int sp  = blockIdx.x - b * SPLIT;
    const int tid = threadIdx.x;
    const int s   = sp * CHUNK + tid;
    const bool active = (tid < CHUNK) && (s < HoWo);

    const int oy = s / Wo, ox = s - oy * Wo;
    const float* offp = off + ((size_t)b * 2 * KK) * HoWo + s;

    float acc[CO];
#pragma unroll
    for (int o = 0; o < CO; ++o) acc[o] = 0.f;

    for (int pass = 0; pass < NPASS; ++pass) {
        const int cbase = pass * CSPLIT;
        __syncthreads();
        for (int pos = tid; pos < HW; pos += THREADS) {
#pragma unroll
            for (int c = 0; c < CSPLIT; ++c)
                tile[pos * STRIDE + c] = x[((size_t)b * CI + (cbase + c)) * HW + pos];
        }
        __syncthreads();

        if (active) {
            for (int kk = 0; kk < KK; ++kk) {
                const float dy = offp[(size_t)(2 * kk + 0) * HoWo];
                const float dx = offp[(size_t)(2 * kk + 1) * HoWo];
                const float py = (float)(kk / K + oy) + dy;
                const float px = (float)(kk % K + ox) + dx;
                const float y0f = floorf(py), x0f = floorf(px);
                const float wy = py - y0f, wx = px - x0f;
                const int y0 = (int)y0f, x0 = (int)x0f;
                const int y1 = y0 + 1,   x1 = x0 + 1;

                const float m00 = (y0 >= 0 && y0 < H && x0 >= 0 && x0 < W) ? 1.f : 0.f;
                const float m01 = (y0 >= 0 && y0 < H && x1 >= 0 && x1 < W) ? 1.f : 0.f;
                const float m10 = (y1 >= 0 && y1 < H && x0 >= 0 && x0 < W) ? 1.f : 0.f;
                const float m11 = (y1 >= 0 && y1 < H && x1 >= 0 && x1 < W) ? 1.f : 0.f;

                const float w00 = (1.f - wy) * (1.f - wx) * m00;
                const float w01 = (1.f - wy) * wx         * m01;
                const float w10 = wy         * (1.f - wx) * m10;
                const float w11 = wy         * wx         * m11;

                const int y0c = min(max(y0, 0), H - 1), y1c = min(max(y1, 0), H - 1);
                const int x0c = min(max(x0, 0), W - 1), x1c = min(max(x1, 0), W - 1);
                const int i00 = (y0c * W + x0c) * STRIDE;
                const int i01 = (y0c * W + x1c) * STRIDE;
                const int i10 = (y1c * W + x0c) * STRIDE;
                const int i11 = (y1c * W + x1c) * STRIDE;

                if constexpr (CSPLIT % 4 == 0) {
#pragma unroll
                    for (int cg = 0; cg < CSPLIT; cg += 4) {
                        const f32x4 v00 = *(const f32x4*)(tile + i00 + cg);
                        const f32x4 v01 = *(const f32x4*)(tile + i01 + cg);
                        const f32x4 v10 = *(const f32x4*)(tile + i10 + cg);
                        const f32x4 v11 = *(const f32x4*)(tile + i11 + cg);
#pragma unroll
                        for (int j = 0; j < 4; ++j) {
                            const float sv = fmaf(v11[j], w11, fmaf(v10[j], w10,
                                             fmaf(v01[j], w01, v00[j] * w00)));
#pragma unroll
                            for (int o = 0; o < CO; ++o)
                                acc[o] = fmaf(sv, w[(size_t)(o * CI + cbase + cg + j) * KK + kk], acc[o]);
                        }
                    }
                } else {
                    const float sv = fmaf(tile[i11], w11, fmaf(tile[i10], w10,
                                     fmaf(tile[i01], w01, tile[i00] * w00)));
#pragma unroll
                    for (int o = 0; o < CO; ++o)
                        acc[o] = fmaf(sv, w[(size_t)(o * CI + cbase) * KK + kk], acc[o]);
                }
            }
        }
    }

    if (active) {
#pragma unroll
        for (int o = 0; o < CO; ++o) {
            float v = acc[o] + bias[o];
            if (RELU) v = fmaxf(v, 0.f);
            if (OUTPL) {
                const size_t oi = (((size_t)b * NPO + (o >> 3)) * HoWo + s) * 8 + (o & 7);
                const ushort_t h = bf16_trunc(v);
                oHi[oi] = h;
                oLo[oi] = bf16_trunc(v - bf16_to_f(h));
            } else {
                outF[((size_t)b * CO + o) * HoWo + s] = v;
            }
        }
    }
}

// ---------------------------------------------------------------------------
// Register-tiled direct VALID conv (stages 1 and 6 offset convs).
// ---------------------------------------------------------------------------
template<int K, int CI, int NOC, int OC, int H, int W, int Ho, int Wo, int PIX>
__global__ __launch_bounds__(256)
void conv_tile(const float* __restrict__ x, const float* __restrict__ w,
               const float* __restrict__ bias, float* __restrict__ out)
{
    constexpr int KK   = K * K;
    constexpr int HoWo = Ho * Wo;
    constexpr int WoG  = (Wo + PIX - 1) / PIX;
    constexpr int G    = Ho * WoG;
    constexpr int XV   = PIX + K - 1;

    const int oc0   = blockIdx.y * NOC;
    const int g_all = blockIdx.x * 256 + threadIdx.x;
    const int b     = g_all / G;
    const int g     = g_all - b * G;
    const int oy    = g / WoG;
    const int ox0   = (g - oy * WoG) * PIX;

    const float* xbp = x + (b * CI) * (H * W) + oy * W + ox0;
    const float* wp  = w + oc0 * (CI * KK);

    float acc[PIX][NOC];
#pragma unroll
    for (int p = 0; p < PIX; ++p)
#pragma unroll
        for (int j = 0; j < NOC; ++j) acc[p][j] = bias[oc0 + j];

    const int lim = W - 1 - ox0;

    for (int ci = 0; ci < CI; ++ci) {
        const float* xc = xbp + ci * (H * W);
#pragma unroll
        for (int ky = 0; ky < K; ++ky) {
            float xv[XV];
#pragma unroll
            for (int i = 0; i < XV; ++i) {
                const int off = (i <= lim) ? i : lim;
                xv[i] = xc[ky * W + off];
            }
#pragma unroll
            for (int kx = 0; kx < K; ++kx) {
#pragma unroll
                for (int p = 0; p < PIX; ++p) {
                    const float v = xv[p + kx];
#pragma unroll
                    for (int j = 0; j < NOC; ++j)
                        acc[p][j] = fmaf(v, wp[j * (CI * KK) + ci * KK + ky * K + kx], acc[p][j]);
                }
            }
        }
    }

    float* op = out + (b * OC + oc0) * HoWo + oy * Wo + ox0;
#pragma unroll
    for (int p = 0; p < PIX; ++p) {
        if (ox0 + p < Wo) {
#pragma unroll
            for (int j = 0; j < NOC; ++j) op[j * HoWo + p] = acc[p][j];
        }
    }
}

// ---------------------------------------------------------------------------
// FC weight transpose + coalesced FC.
// ---------------------------------------------------------------------------
template<int IN, int OUT>
__global__ __launch_bounds__(256)
void wtrans(const float* __restrict__ w, float* __restrict__ wt)
{
    const int idx = blockIdx.x * 256 + threadIdx.x;
    if (idx >= IN * OUT) return;
    const int i = idx / OUT, j = idx - i * OUT;
    wt[idx] = w[(size_t)j * IN + i];
}

template<int IN, int OUT, bool RELU>
__global__ __launch_bounds__(256)
void fc_t(const float* __restrict__ h, const float* __restrict__ wt,
          const float* __restrict__ bias, float* __restrict__ out, int B)
{
    const int idx = blockIdx.x * 256 + threadIdx.x;
    if (idx >= B * OUT) return;
    const int b = idx / OUT;
    const int j = idx - b * OUT;
    const float* hb = h + (size_t)b * IN;
    float acc = bias[j];
#pragma unroll 4
    for (int i = 0; i < IN; ++i)
        acc = fmaf(hb[i], wt[(size_t)i * OUT + j], acc);
    if (RELU) acc = fmaxf(acc, 0.f);
    out[idx] = acc;
}

// ---------------------------------------------------------------------------
extern "C" void kernel_launch(void* const* d_in, const int* in_sizes, int n_in,
                              void* d_out, int out_size, void* d_ws, size_t ws_size,
                              hipStream_t stream)
{
    const int B = 512;
    const float* x = (const float*)d_in[0];
    const float *ow[6], *ob[6], *w[6], *bi[6];
    for (int i = 0; i < 6; ++i) {
        ow[i] = (const float*)d_in[1 + 4 * i];
        ob[i] = (const float*)d_in[2 + 4 * i];
        w[i]  = (const float*)d_in[3 + 4 * i];
        bi[i] = (const float*)d_in[4 + 4 * i];
    }
    const float* fc1w = (const float*)d_in[25];
    const float* fc1b = (const float*)d_in[26];
    const float* fc2w = (const float*)d_in[27];
    const float* fc2b = (const float*)d_in[28];
    float* out = (float*)d_out;

    float* P   = (float*)d_ws;        // 14M floats
    float* Q   = P  + 14000000;       // 14M floats
    float* OFF = Q  + 14000000;       // 18.2M floats
    float* Z   = OFF + 18200000;      // fc intermediate
    ushort_t* WBhi = (ushort_t*)(Z + 200000);
    ushort_t* WBlo = WBhi + 200000;
    ushort_t* WDhi = WBlo + 200000;
    ushort_t* WDlo = WDhi + 200000;
    float* WT1 = (float*)(WDlo + 200000);
    float* WT2 = WT1 + 173056;

    const dim3 blk(256);
    #define GRIDT(Ho, Wo, PIX, NG) dim3((B * (Ho) * (((Wo) + (PIX) - 1) / (PIX)) + 255) / 256, (NG), 1)
    #define CEILDIV(a, b) (((a) + (b) - 1) / (b))

    // plane regions (channel-grouped layout, same sizes as R14)
    ushort_t* PL2h = (ushort_t*)Q;  ushort_t* PL2l = PL2h + (size_t)(B * 961 + 2048) * 16;
    ushort_t* PL3h = (ushort_t*)P;  ushort_t* PL3l = PL3h + (size_t)(B * 841 + 2048) * 32;
    ushort_t* PL4h = (ushort_t*)Q;  ushort_t* PL4l = PL4h + (size_t)(B * 625 + 2048) * 16;
    ushort_t* PL5h = (ushort_t*)P;  ushort_t* PL5l = PL5h + (size_t)(B * 361 + 2048) * 16;

    // ---- stage 1: input x (CI=1). conv_tile -> OFF; deform_lds -> PL2 ----
    conv_tile<3, 1, 6, 18, 33, 33, 31, 31, 4><<<GRIDT(31, 31, 4, 3), blk, 0, stream>>>(x, ow[0], ob[0], OFF);
    deform_lds<3, 1, 16, 33, 33, 31, 31, true, 1, 1, 512, 2, true><<<dim3(B * 2), dim3(512), 0, stream>>>(x, OFF, w[0], bi[0], nullptr, PL2h, PL2l);

    // ---- stage 2: CI=16 K=3 31x31->29x29 OC(off)=18 CO=32. PL2 -> PL3 ----
    {
        const int Mv = B * 841;
        wprep<16, 9, 10, 32, 18><<<CEILDIV(10 * 32 * 16, 256), blk, 0, stream>>>(ow[1], WBhi, WBlo);
        conv_mfma<16, 3, 31, 31, 29, 29, 18, 2, 2, 5><<<dim3(CEILDIV(Mv, 256), 1), blk, 0, stream>>>(PL2h, PL2l, WBhi, WBlo, ob[1], OFF, Mv);
        wprep_d<16, 9, 12, 32, 32><<<CEILDIV(2 * 12 * 32 * 8, 256), blk, 0, stream>>>(w[1], WDhi, WDlo);
        deform_mfma<3, 16, 32, 31, 31, 29, 29, true, 8, 12, true><<<dim3(B * 7), dim3(512), 0, stream>>>(PL2h, PL2l, OFF, WDhi, WDlo, bi[1], nullptr, PL3h, PL3l);
    }
    // ---- stage 3: CI=32 K=5 29x29->25x25 OC(off)=50 CO=16 (no relu). PL3 -> PL4 ----
    {
        const int Mv = B * 625;
        wprep<32, 25, 25, 64, 50><<<CEILDIV(25 * 64 * 32, 256), blk, 0, stream>>>(ow[2], WBhi, WBlo);
        conv_mfma<32, 5, 29, 29, 25, 25, 50, 4, 4, 25><<<dim3(CEILDIV(Mv, 256), 1), blk, 0, stream>>>(PL3h, PL3l, WBhi, WBlo, ob[2], OFF, Mv);
        wprep_d<32, 25, 28, 16, 16><<<CEILDIV(4 * 28 * 16 * 8, 256), blk, 0, stream>>>(w[2], WDhi, WDlo);
        deform_mfma<5, 32, 16, 29, 29, 25, 25, false, 8, 28, true><<<dim3(B * 5), dim3(512), 0, stream>>>(PL3h, PL3l, OFF, WDhi, WDlo, bi[2], nullptr, PL4h, PL4l);
    }
    // ---- stage 4: CI=16 K=7 25x25->19x19 OC(off)=98 CO=16. PL4 -> PL5 ----
    {
        const int Mv = B * 361;
        wprep<16, 49, 50, 112, 98><<<CEILDIV(50 * 112 * 16, 256), blk, 0, stream>>>(ow[3], WBhi, WBlo);
        conv_mfma<16, 7, 25, 25, 19, 19, 98, 7, 4, 25><<<dim3(CEILDIV(Mv, 256), 2), blk, 0, stream>>>(PL4h, PL4l, WBhi, WBlo, ob[3], OFF, Mv);
        wprep_d<16, 49, 52, 16, 16><<<CEILDIV(2 * 52 * 16 * 8, 256), blk, 0, stream>>>(w[3], WDhi, WDlo);
        deform_mfma<7, 16, 16, 25, 25, 19, 19, true, 8, 52, true><<<dim3(B * 3), dim3(512), 0, stream>>>(PL4h, PL4l, OFF, WDhi, WDlo, bi[3], nullptr, PL5h, PL5l);
    }
    // ---- stage 5: CI=16 K=5 19x19->15x15 OC(off)=50 CO=8. PL5 -> Q (fp32 NCHW) ----
    {
        const int Mv = B * 225;
        wprep<16, 25, 26, 64, 50><<<CEILDIV(26 * 64 * 16, 256), blk, 0, stream>>>(ow[4], WBhi, WBlo);
        conv_mfma<16, 5, 19, 19, 15, 15, 50, 4, 4, 13><<<dim3(CEILDIV(Mv, 256), 1), blk, 0, stream>>>(PL5h, PL5l, WBhi, WBlo, ob[4], OFF, Mv);
        wprep_d<16, 25, 28, 16, 8><<<CEILDIV(2 * 28 * 16 * 8, 256), blk, 0, stream>>>(w[4], WDhi, WDlo);
        deform_mfma<5, 16, 8, 19, 19, 15, 15, true, 4, 28, false><<<dim3(B * 4), dim3(256), 0, stream>>>(PL5h, PL5l, OFF, WDhi, WDlo, bi[4], Q, nullptr, nullptr);
    }
    // ---- stage 6: CI=8 K=3 15x15->13x13 CO=4. Q -> P (fp32 NCHW) ----
    conv_tile<3, 8, 6, 18, 15, 15, 13, 13, 4><<<GRIDT(13, 13, 4, 3), blk, 0, stream>>>(Q, ow[5], ob[5], OFF);
    deform_lds<3, 8, 4, 15, 15, 13, 13, true, 8, 12, 192, 1, false><<<dim3(B), dim3(192), 0, stream>>>(Q, OFF, w[5], bi[5], P, nullptr, nullptr);

    // ---- FC head (reads P = 512 x 4 x 13 x 13) ----
    wtrans<676, 256><<<CEILDIV(676 * 256, 256), blk, 0, stream>>>(fc1w, WT1);
    wtrans<256, 10><<<CEILDIV(256 * 10, 256), blk, 0, stream>>>(fc2w, WT2);
    fc_t<676, 256, true><<<dim3(CEILDIV(B * 256, 256)), blk, 0, stream>>>(P, WT1, fc1b, Z, B);
    fc_t<256, 10, false><<<dim3(CEILDIV(B * 10, 256)), blk, 0, stream>>>(Z, WT2, fc2b, out, B);

    #undef GRIDT
    #undef CEILDIV
}